// Round 1
// baseline (426.872 us; speedup 1.0000x reference)
//
#include <hip/hip_runtime.h>
#include <hip/hip_bf16.h>
#include <math.h>

typedef short bf16x8 __attribute__((ext_vector_type(8)));
typedef float f32x4 __attribute__((ext_vector_type(4)));

static __device__ __forceinline__ unsigned short f2bf(float f) {
    unsigned int u = __float_as_uint(f);
    unsigned int r = (u + 0x7fffu + ((u >> 16) & 1u)) >> 16;
    return (unsigned short)r;
}

static __device__ __forceinline__ float gelu_f(float x) {
    return 0.5f * x * (1.f + erff(x * 0.70710678118654752f));
}

static __device__ __forceinline__ int ldsmap(int i) { return i + (i >> 5); }

static __device__ __forceinline__ int rev4(int k) {
    int d0 = k % 10; k /= 10;
    int d1 = k % 10; k /= 10;
    int d2 = k % 10; int d3 = k / 10;
    return d0 * 1000 + d1 * 100 + d2 * 10 + d3;
}

// ---------------------------------------------------------------------------
// FFT kernel: one block per batch row. Packs x into complex z (len 10000),
// subtracts mean, 4x radix-10 DIF stages in LDS, real-FFT untangle,
// h = log1p(|X|), c = h^2/(||h||+1e-8). Writes bf16 padded to K=10240.
// ---------------------------------------------------------------------------
__global__ __launch_bounds__(512)
void fft_kernel(const float* __restrict__ x,
                unsigned short* __restrict__ hb,
                unsigned short* __restrict__ cb)
{
    __shared__ float reb[10320];
    __shared__ float imb[10320];
    __shared__ float redbuf[8];

    const int b = blockIdx.x;
    const int tid = threadIdx.x;
    const int lane = tid & 63;
    const int wv = tid >> 6;
    const float* xr = x + (size_t)b * 20000;

    // load + pack + accumulate sum
    float sum = 0.f;
    for (int i = tid; i < 20000; i += 512) {
        float v = xr[i];
        sum += v;
        int n = i >> 1;
        if (i & 1) imb[ldsmap(n)] = v;
        else       reb[ldsmap(n)] = v;
    }
    // block reduce sum (512 threads)
    #pragma unroll
    for (int o = 32; o; o >>= 1) sum += __shfl_xor(sum, o);
    __syncthreads();                  // pack complete before redbuf use + subtract
    if (lane == 0) redbuf[wv] = sum;
    __syncthreads();
    float tot = 0.f;
    #pragma unroll
    for (int i = 0; i < 8; ++i) tot += redbuf[i];
    const float mean = tot * (1.f / 20000.f);

    for (int n = tid; n < 10000; n += 512) {
        reb[ldsmap(n)] -= mean;
        imb[ldsmap(n)] -= mean;
    }
    __syncthreads();

    const float W10R[10] = {1.f, 0.80901699f, 0.30901699f, -0.30901699f, -0.80901699f,
                            -1.f, -0.80901699f, -0.30901699f, 0.30901699f, 0.80901699f};
    const float W10I[10] = {0.f, -0.58778525f, -0.95105652f, -0.95105652f, -0.58778525f,
                            0.f, 0.58778525f, 0.95105652f, 0.95105652f, 0.58778525f};

    // 4 radix-10 DIF stages (in-place, output digit-reversed)
    #pragma unroll
    for (int s = 0; s < 4; ++s) {
        const int L = (s == 0) ? 1000 : (s == 1) ? 100 : (s == 2) ? 10 : 1;
        for (int w = tid; w < 1000; w += 512) {
            int g = w / L;
            int j = w - g * L;
            int base = g * (10 * L);
            float ur[10], ui[10];
            #pragma unroll
            for (int u = 0; u < 10; ++u) {
                int idx = ldsmap(base + j + u * L);
                ur[u] = reb[idx];
                ui[u] = imb[idx];
            }
            float sj, cj;
            sincosf(-6.28318530717958648f * (float)j / (float)(10 * L), &sj, &cj);
            float twr = 1.f, twi = 0.f;
            #pragma unroll
            for (int t = 0; t < 10; ++t) {
                float vr = 0.f, vi = 0.f;
                #pragma unroll
                for (int u = 0; u < 10; ++u) {
                    int p = (u * t) % 10;
                    float wr = W10R[p], wi = W10I[p];
                    vr += ur[u] * wr - ui[u] * wi;
                    vi += ur[u] * wi + ui[u] * wr;
                }
                float orr = vr * twr - vi * twi;
                float oii = vr * twi + vi * twr;
                int idx = ldsmap(base + j + t * L);
                reb[idx] = orr;
                imb[idx] = oii;
                float ntr = twr * cj - twi * sj;
                twi = twr * sj + twi * cj;
                twr = ntr;
            }
        }
        __syncthreads();
    }

    // real-FFT untangle + log1p|X|, keep h in registers for the c pass
    float harr[20];
    float sumsq = 0.f;
    unsigned short* hrow = hb + (size_t)b * 10240;
    #pragma unroll
    for (int i = 0; i < 20; ++i) {
        int k = tid + i * 512;
        float hval = 0.f;
        if (k <= 10000) {
            int k1 = (k == 10000) ? 0 : k;
            int k2 = (10000 - k) % 10000;
            int i1 = ldsmap(rev4(k1));
            int i2 = ldsmap(rev4(k2));
            float zr = reb[i1], zi = imb[i1];
            float wr = reb[i2], wi = imb[i2];
            float er = 0.5f * (zr + wr);
            float ei = 0.5f * (zi - wi);
            float odr = 0.5f * (zi + wi);
            float odi = -0.5f * (zr - wr);
            float st, ct;
            sincosf(-3.14159265358979324f * (float)k * (1.f / 10000.f), &st, &ct);
            float xre = er + ct * odr - st * odi;
            float xim = ei + ct * odi + st * odr;
            hval = log1pf(sqrtf(xre * xre + xim * xim));
        }
        harr[i] = hval;
        hrow[k] = f2bf(hval);
        sumsq += hval * hval;
    }
    // block reduce sumsq
    #pragma unroll
    for (int o = 32; o; o >>= 1) sumsq += __shfl_xor(sumsq, o);
    __syncthreads();
    if (lane == 0) redbuf[wv] = sumsq;
    __syncthreads();
    float tsq = 0.f;
    #pragma unroll
    for (int i = 0; i < 8; ++i) tsq += redbuf[i];
    const float inv = 1.f / (sqrtf(tsq) + 1e-8f);

    unsigned short* crow = cb + (size_t)b * 10240;
    #pragma unroll
    for (int i = 0; i < 20; ++i) {
        int k = tid + i * 512;
        crow[k] = f2bf(harr[i] * harr[i] * inv);
    }
}

// ---------------------------------------------------------------------------
// Pack W0 -> bf16 padded; sigmoid(alpha0) -> bf16 padded (pads are zero).
// grid (40, 256, 2), block 256
// ---------------------------------------------------------------------------
__global__ __launch_bounds__(256)
void pack0_kernel(const float* __restrict__ W0, const float* __restrict__ A0,
                  unsigned short* __restrict__ Wb, unsigned short* __restrict__ Sb)
{
    int col = blockIdx.x * 256 + threadIdx.x;   // 0..10239
    int row = blockIdx.y;                        // 0..255
    if (blockIdx.z == 0) {
        float v = (col < 10001) ? W0[(size_t)row * 10001 + col] : 0.f;
        Wb[(size_t)row * 10240 + col] = f2bf(v);
    } else {
        float v = (col < 10001) ? 1.f / (1.f + expf(-A0[(size_t)row * 10001 + col])) : 0.f;
        Sb[(size_t)row * 10240 + col] = f2bf(v);
    }
}

// ---------------------------------------------------------------------------
// Transpose small weights to [d][h] fp32; apply sigmoid to alphas.
// grid 320, block 256 (81920 elements total)
// ---------------------------------------------------------------------------
__global__ __launch_bounds__(256)
void pack_small_kernel(const float* __restrict__ W1, const float* __restrict__ A1,
                       const float* __restrict__ W2, const float* __restrict__ A2,
                       float* __restrict__ W1T, float* __restrict__ S1T,
                       float* __restrict__ W2T, float* __restrict__ S2T)
{
    int idx = blockIdx.x * 256 + threadIdx.x;
    if (idx < 32768) {
        int d = idx >> 7, h = idx & 127;
        W1T[idx] = W1[h * 256 + d];
    } else if (idx < 65536) {
        int o = idx - 32768;
        int d = o >> 7, h = o & 127;
        S1T[o] = 1.f / (1.f + expf(-A1[h * 256 + d]));
    } else if (idx < 73728) {
        int o = idx - 65536;
        int d = o >> 6, h = o & 63;
        W2T[o] = W2[h * 128 + d];
    } else if (idx < 81920) {
        int o = idx - 73728;
        int d = o >> 6, h = o & 63;
        S2T[o] = 1.f / (1.f + expf(-A2[h * 128 + d]));
    }
}

// ---------------------------------------------------------------------------
// Layer-0 dual GEMM (y = h*W0^T and p = c*S0^T), bf16 MFMA 16x16x32,
// BM=128 BN=64 BK=32, split-K=16 (640 each = 20 steps). grid (8,4,16) x 256.
// ---------------------------------------------------------------------------
__global__ __launch_bounds__(256)
void gemm0_kernel(const unsigned short* __restrict__ hb, const unsigned short* __restrict__ cb,
                  const unsigned short* __restrict__ Wb, const unsigned short* __restrict__ Sb,
                  float* __restrict__ Py, float* __restrict__ Pp)
{
    __shared__ unsigned short Ah[128 * 32];
    __shared__ unsigned short Ac[128 * 32];
    __shared__ unsigned short Bw[64 * 32];
    __shared__ unsigned short Bs[64 * 32];

    const int t = threadIdx.x;
    const int b0 = blockIdx.x * 128;
    const int n0 = blockIdx.y * 64;
    const int z = blockIdx.z;
    const int lane = t & 63;
    const int wv = t >> 6;
    const int ml = lane & 15;
    const int q8 = (lane >> 4) * 8;

    f32x4 accY[2][4], accP[2][4];
    #pragma unroll
    for (int mt = 0; mt < 2; ++mt)
        #pragma unroll
        for (int nt = 0; nt < 4; ++nt) {
            accY[mt][nt] = (f32x4){0.f, 0.f, 0.f, 0.f};
            accP[mt][nt] = (f32x4){0.f, 0.f, 0.f, 0.f};
        }

    const int ra = t >> 2;            // 0..63
    const int q = (t & 3) * 8;        // 0,8,16,24
    const int kbase = z * 640;

    for (int step = 0; step < 20; ++step) {
        const int k0 = kbase + step * 32;
        __syncthreads();   // LDS reuse guard
        {
            size_t ga = (size_t)(b0 + ra) * 10240 + k0 + q;
            *(int4*)&Ah[ra * 32 + q] = *(const int4*)&hb[ga];
            *(int4*)&Ac[ra * 32 + q] = *(const int4*)&cb[ga];
            size_t ga2 = (size_t)(b0 + ra + 64) * 10240 + k0 + q;
            *(int4*)&Ah[(ra + 64) * 32 + q] = *(const int4*)&hb[ga2];
            *(int4*)&Ac[(ra + 64) * 32 + q] = *(const int4*)&cb[ga2];
            size_t gb = (size_t)(n0 + ra) * 10240 + k0 + q;
            *(int4*)&Bw[ra * 32 + q] = *(const int4*)&Wb[gb];
            *(int4*)&Bs[ra * 32 + q] = *(const int4*)&Sb[gb];
        }
        __syncthreads();

        bf16x8 ah[2], ac[2], bw[4], bs[4];
        #pragma unroll
        for (int mt = 0; mt < 2; ++mt) {
            int mrow = wv * 32 + mt * 16 + ml;
            ah[mt] = *(const bf16x8*)&Ah[mrow * 32 + q8];
            ac[mt] = *(const bf16x8*)&Ac[mrow * 32 + q8];
        }
        #pragma unroll
        for (int nt = 0; nt < 4; ++nt) {
            int nrow = nt * 16 + ml;
            bw[nt] = *(const bf16x8*)&Bw[nrow * 32 + q8];
            bs[nt] = *(const bf16x8*)&Bs[nrow * 32 + q8];
        }
        #pragma unroll
        for (int mt = 0; mt < 2; ++mt)
            #pragma unroll
            for (int nt = 0; nt < 4; ++nt) {
                accY[mt][nt] = __builtin_amdgcn_mfma_f32_16x16x32_bf16(ah[mt], bw[nt], accY[mt][nt], 0, 0, 0);
                accP[mt][nt] = __builtin_amdgcn_mfma_f32_16x16x32_bf16(ac[mt], bs[nt], accP[mt][nt], 0, 0, 0);
            }
    }

    const int rq = (lane >> 4) * 4;
    #pragma unroll
    for (int mt = 0; mt < 2; ++mt)
        #pragma unroll
        for (int nt = 0; nt < 4; ++nt)
            #pragma unroll
            for (int r = 0; r < 4; ++r) {
                int m = b0 + wv * 32 + mt * 16 + rq + r;
                int n = n0 + nt * 16 + ml;
                size_t o = ((size_t)z * 1024 + m) * 256 + n;
                Py[o] = accY[mt][nt][r];
                Pp[o] = accP[mt][nt][r];
            }
}

// ---------------------------------------------------------------------------
// Combine splits + bias + plastic + LayerNorm(256) + GELU + c for next layer.
// grid 1024 (one per row), block 256
// ---------------------------------------------------------------------------
__global__ __launch_bounds__(256)
void combine0_kernel(const float* __restrict__ Py, const float* __restrict__ Pp,
                     const float* __restrict__ b0v, const float* __restrict__ eta0p,
                     const float* __restrict__ g0, const float* __restrict__ be0,
                     float* __restrict__ h1, float* __restrict__ c1)
{
    __shared__ float red[4];
    const int b = blockIdx.x;
    const int h = threadIdx.x;
    const int lane = h & 63;
    const int wv = h >> 6;

    float ys = 0.f, ps = 0.f;
    for (int s = 0; s < 16; ++s) {
        size_t o = ((size_t)s * 1024 + b) * 256 + h;
        ys += Py[o];
        ps += Pp[o];
    }
    float y = ys + b0v[h];
    float v = y + eta0p[0] * tanhf(y) * ps;

    // LN over 256: reduce sum
    float s1 = v;
    #pragma unroll
    for (int o = 32; o; o >>= 1) s1 += __shfl_xor(s1, o);
    __syncthreads();
    if (lane == 0) red[wv] = s1;
    __syncthreads();
    float sum = red[0] + red[1] + red[2] + red[3];

    float s2 = v * v;
    #pragma unroll
    for (int o = 32; o; o >>= 1) s2 += __shfl_xor(s2, o);
    __syncthreads();
    if (lane == 0) red[wv] = s2;
    __syncthreads();
    float sumsq = red[0] + red[1] + red[2] + red[3];

    float mu = sum * (1.f / 256.f);
    float var = sumsq * (1.f / 256.f) - mu * mu;
    float u = (v - mu) * rsqrtf(var + 1e-5f) * g0[h] + be0[h];
    float gl = gelu_f(u);

    float s3 = gl * gl;
    #pragma unroll
    for (int o = 32; o; o >>= 1) s3 += __shfl_xor(s3, o);
    __syncthreads();
    if (lane == 0) red[wv] = s3;
    __syncthreads();
    float gsq = red[0] + red[1] + red[2] + red[3];
    float inv = 1.f / (sqrtf(gsq) + 1e-8f);

    h1[(size_t)b * 256 + h] = gl;
    c1[(size_t)b * 256 + h] = gl * gl * inv;
}

// ---------------------------------------------------------------------------
// Tail: layers 1,2 + head, fp32. 8 rows per block. grid 128, block 256.
// ---------------------------------------------------------------------------
__global__ __launch_bounds__(256)
void tail_kernel(const float* __restrict__ h1, const float* __restrict__ c1,
                 const float* __restrict__ W1T, const float* __restrict__ S1T,
                 const float* __restrict__ b1, const float* __restrict__ eta1p,
                 const float* __restrict__ g1, const float* __restrict__ be1,
                 const float* __restrict__ W2T, const float* __restrict__ S2T,
                 const float* __restrict__ b2, const float* __restrict__ eta2p,
                 const float* __restrict__ g2, const float* __restrict__ be2,
                 const float* __restrict__ hw, const float* __restrict__ hbod,
                 float* __restrict__ out)
{
    __shared__ float sh[8][256];
    __shared__ float sc[8][256];
    __shared__ float sv[8][128];
    __shared__ float sh2[8][128];
    __shared__ float sc2[8][128];
    __shared__ float sv2[8][64];

    const int t = threadIdx.x;
    const int b0 = blockIdx.x * 8;
    const int lane = t & 63;
    const int wv = t >> 6;

    #pragma unroll
    for (int i = 0; i < 8; ++i) {
        int idx = t + i * 256;
        int r = idx >> 8, d = idx & 255;
        sh[r][d] = h1[(size_t)(b0 + r) * 256 + d];
        sc[r][d] = c1[(size_t)(b0 + r) * 256 + d];
    }
    __syncthreads();

    // layer 1: 128 outputs x 8 rows
    const int hcol = t & 127;
    const int r2 = t >> 7;
    float ya[4] = {0.f, 0.f, 0.f, 0.f};
    float pa[4] = {0.f, 0.f, 0.f, 0.f};
    for (int d = 0; d < 256; ++d) {
        float w = W1T[d * 128 + hcol];
        float s = S1T[d * 128 + hcol];
        #pragma unroll
        for (int i = 0; i < 4; ++i) {
            int r = r2 * 4 + i;
            ya[i] += sh[r][d] * w;
            pa[i] += sc[r][d] * s;
        }
    }
    const float e1 = eta1p[0];
    #pragma unroll
    for (int i = 0; i < 4; ++i) {
        int r = r2 * 4 + i;
        float y = ya[i] + b1[hcol];
        sv[r][hcol] = y + e1 * tanhf(y) * pa[i];
    }
    __syncthreads();

    // LN(128) + gelu + c2 : each wave handles 2 rows
    #pragma unroll
    for (int rr = 0; rr < 2; ++rr) {
        int r = wv * 2 + rr;
        float v0 = sv[r][lane];
        float v1 = sv[r][lane + 64];
        float s = v0 + v1, sq = v0 * v0 + v1 * v1;
        #pragma unroll
        for (int o = 32; o; o >>= 1) { s += __shfl_xor(s, o); sq += __shfl_xor(sq, o); }
        float mu = s * (1.f / 128.f);
        float var = sq * (1.f / 128.f) - mu * mu;
        float rs = rsqrtf(var + 1e-5f);
        float u0 = (v0 - mu) * rs * g1[lane] + be1[lane];
        float u1 = (v1 - mu) * rs * g1[lane + 64] + be1[lane + 64];
        float ge0 = gelu_f(u0);
        float ge1 = gelu_f(u1);
        float gsq = ge0 * ge0 + ge1 * ge1;
        #pragma unroll
        for (int o = 32; o; o >>= 1) gsq += __shfl_xor(gsq, o);
        float inv = 1.f / (sqrtf(gsq) + 1e-8f);
        sh2[r][lane] = ge0; sh2[r][lane + 64] = ge1;
        sc2[r][lane] = ge0 * ge0 * inv; sc2[r][lane + 64] = ge1 * ge1 * inv;
    }
    __syncthreads();

    // layer 2: 64 outputs x 8 rows
    const int h2c = t & 63;
    const int r4 = t >> 6;
    float yb[2] = {0.f, 0.f};
    float pb[2] = {0.f, 0.f};
    for (int d = 0; d < 128; ++d) {
        float w = W2T[d * 64 + h2c];
        float s = S2T[d * 64 + h2c];
        #pragma unroll
        for (int i = 0; i < 2; ++i) {
            int r = r4 * 2 + i;
            yb[i] += sh2[r][d] * w;
            pb[i] += sc2[r][d] * s;
        }
    }
    const float e2 = eta2p[0];
    #pragma unroll
    for (int i = 0; i < 2; ++i) {
        int r = r4 * 2 + i;
        float y = yb[i] + b2[h2c];
        sv2[r][h2c] = y + e2 * tanhf(y) * pb[i];
    }
    __syncthreads();

    // LN(64) + gelu + head : each wave 2 rows
    #pragma unroll
    for (int rr = 0; rr < 2; ++rr) {
        int r = wv * 2 + rr;
        float v0 = sv2[r][lane];
        float s = v0, sq = v0 * v0;
        #pragma unroll
        for (int o = 32; o; o >>= 1) { s += __shfl_xor(s, o); sq += __shfl_xor(sq, o); }
        float mu = s * (1.f / 64.f);
        float var = sq * (1.f / 64.f) - mu * mu;
        float rs = rsqrtf(var + 1e-5f);
        float u = (v0 - mu) * rs * g2[lane] + be2[lane];
        float g = gelu_f(u);
        float hc = g * hw[lane];
        #pragma unroll
        for (int o = 32; o; o >>= 1) hc += __shfl_xor(hc, o);
        if (lane == 0) out[b0 + r] = hc + hbod[0];
    }
}

// ---------------------------------------------------------------------------
extern "C" void kernel_launch(void* const* d_in, const int* in_sizes, int n_in,
                              void* d_out, int out_size, void* d_ws, size_t ws_size,
                              hipStream_t stream)
{
    const float* x    = (const float*)d_in[0];
    const float* W0   = (const float*)d_in[1];
    const float* A0   = (const float*)d_in[2];
    const float* b0   = (const float*)d_in[3];
    const float* eta0 = (const float*)d_in[4];
    const float* g0   = (const float*)d_in[5];
    const float* be0  = (const float*)d_in[6];
    const float* W1   = (const float*)d_in[7];
    const float* A1   = (const float*)d_in[8];
    const float* b1   = (const float*)d_in[9];
    const float* eta1 = (const float*)d_in[10];
    const float* g1   = (const float*)d_in[11];
    const float* be1  = (const float*)d_in[12];
    const float* W2   = (const float*)d_in[13];
    const float* A2   = (const float*)d_in[14];
    const float* b2   = (const float*)d_in[15];
    const float* eta2 = (const float*)d_in[16];
    const float* g2   = (const float*)d_in[17];
    const float* be2  = (const float*)d_in[18];
    const float* hw   = (const float*)d_in[19];
    const float* hbod = (const float*)d_in[20];
    float* out = (float*)d_out;

    char* w = (char*)d_ws;
    unsigned short* hb  = (unsigned short*)(w + 0);          // 1024*10240*2 = 20971520
    unsigned short* cb  = (unsigned short*)(w + 20971520);   // 20971520
    unsigned short* Wb0 = (unsigned short*)(w + 41943040);   // 256*10240*2 = 5242880
    unsigned short* Sb0 = (unsigned short*)(w + 47185920);   // 5242880
    float* Py  = (float*)(w + 52428800);                     // 16*1024*256*4 = 16777216
    float* Pp  = (float*)(w + 69206016);                     // 16777216
    float* h1  = (float*)(w + 85983232);                     // 1048576
    float* c1  = (float*)(w + 87031808);                     // 1048576
    float* W1T = (float*)(w + 88080384);                     // 131072
    float* S1T = (float*)(w + 88211456);                     // 131072
    float* W2T = (float*)(w + 88342528);                     // 32768
    float* S2T = (float*)(w + 88375296);                     // 32768
    // total = 88408064 bytes

    hipLaunchKernelGGL(fft_kernel, dim3(1024), dim3(512), 0, stream, x, hb, cb);
    hipLaunchKernelGGL(pack0_kernel, dim3(40, 256, 2), dim3(256), 0, stream, W0, A0, Wb0, Sb0);
    hipLaunchKernelGGL(pack_small_kernel, dim3(320), dim3(256), 0, stream, W1, A1, W2, A2, W1T, S1T, W2T, S2T);
    hipLaunchKernelGGL(gemm0_kernel, dim3(8, 4, 16), dim3(256), 0, stream, hb, cb, Wb0, Sb0, Py, Pp);
    hipLaunchKernelGGL(combine0_kernel, dim3(1024), dim3(256), 0, stream, Py, Pp, b0, eta0, g0, be0, h1, c1);
    hipLaunchKernelGGL(tail_kernel, dim3(128), dim3(256), 0, stream, h1, c1, W1T, S1T, b1, eta1, g1, be1,
                       W2T, S2T, b2, eta2, g2, be2, hw, hbod, out);
}

// Round 2
// 352.197 us; speedup vs baseline: 1.2120x; 1.2120x over previous
//
#include <hip/hip_runtime.h>
#include <hip/hip_bf16.h>
#include <math.h>

typedef short bf16x8 __attribute__((ext_vector_type(8)));
typedef float f32x4 __attribute__((ext_vector_type(4)));

static __device__ __forceinline__ unsigned short f2bf(float f) {
    unsigned int u = __float_as_uint(f);
    unsigned int r = (u + 0x7fffu + ((u >> 16) & 1u)) >> 16;
    return (unsigned short)r;
}

static __device__ __forceinline__ float gelu_f(float x) {
    return 0.5f * x * (1.f + erff(x * 0.70710678118654752f));
}

// LDS index skew: breaks power-of-10 stride bank patterns while keeping
// footprint <= 80KB so 2 blocks fit per CU (160 KiB LDS).
static __device__ __forceinline__ int ldsmap(int i) { return i + (i >> 6); }

static __device__ __forceinline__ int rev4(int k) {
    int d0 = k % 10; k /= 10;
    int d1 = k % 10; k /= 10;
    int d2 = k % 10; int d3 = k / 10;
    return d0 * 1000 + d1 * 100 + d2 * 10 + d3;
}

// forward 5-point DFT (W5 = e^{-2pi i/5}), Winograd-style
static __device__ __forceinline__ void dft5(
    float a0r, float a0i, float a1r, float a1i, float a2r, float a2i,
    float a3r, float a3i, float a4r, float a4i,
    float* Xr, float* Xi)
{
    const float c1 = 0.30901699437494742f, c2 = -0.80901699437494745f;
    const float s1 = 0.95105651629515357f, s2 = 0.58778525229247312f;
    float t1r = a1r + a4r, t1i = a1i + a4i;
    float d1r = a1r - a4r, d1i = a1i - a4i;
    float t2r = a2r + a3r, t2i = a2i + a3i;
    float d2r = a2r - a3r, d2i = a2i - a3i;
    Xr[0] = a0r + t1r + t2r; Xi[0] = a0i + t1i + t2i;
    float m1r = a0r + c1 * t1r + c2 * t2r, m1i = a0i + c1 * t1i + c2 * t2i;
    float m2r = a0r + c2 * t1r + c1 * t2r, m2i = a0i + c2 * t1i + c1 * t2i;
    float n1r = s1 * d1r + s2 * d2r, n1i = s1 * d1i + s2 * d2i;
    float n2r = s2 * d1r - s1 * d2r, n2i = s2 * d1i - s1 * d2i;
    Xr[1] = m1r + n1i; Xi[1] = m1i - n1r;
    Xr[4] = m1r - n1i; Xi[4] = m1i + n1r;
    Xr[2] = m2r + n2i; Xi[2] = m2i - n2r;
    Xr[3] = m2r - n2i; Xi[3] = m2i + n2r;
}

// ---------------------------------------------------------------------------
// Twiddle tables: gtw[m] = e^{-2pi i m/10000} (m<10000), ut[k] = e^{-i pi k/10000}
// ---------------------------------------------------------------------------
__global__ __launch_bounds__(256)
void twid_init(float2* __restrict__ gtw, float2* __restrict__ ut)
{
    int i = blockIdx.x * 256 + threadIdx.x;
    if (i < 10000) {
        float ph = -6.28318530717958648f * (float)i * (1.f / 10000.f);
        float s, c; sincosf(ph, &s, &c);
        gtw[i] = make_float2(c, s);
    }
    if (i < 10241) {
        float ph = -3.14159265358979324f * (float)i * (1.f / 10000.f);
        float s, c; sincosf(ph, &s, &c);
        ut[i] = make_float2(c, s);
    }
}

// ---------------------------------------------------------------------------
// FFT kernel: one block per batch row. Packs x into complex z (len 10000),
// subtracts mean, 4x radix-10 DIF stages (each = 2x DFT5 + combine) in LDS,
// real-FFT untangle, h = log1p(|X|), c = h^2/(||h||+1e-8). bf16, K-pad 10240.
// ---------------------------------------------------------------------------
__global__ __launch_bounds__(512, 4)
void fft_kernel(const float* __restrict__ x,
                const float2* __restrict__ gtw,
                const float2* __restrict__ ut,
                unsigned short* __restrict__ hb,
                unsigned short* __restrict__ cb)
{
    __shared__ float reb[10156];
    __shared__ float imb[10156];
    __shared__ float redbuf[8];

    const int b = blockIdx.x;
    const int tid = threadIdx.x;
    const int lane = tid & 63;
    const int wv = tid >> 6;
    const float* xr = x + (size_t)b * 20000;

    // load + pack + accumulate sum
    float sum = 0.f;
    for (int i = tid; i < 20000; i += 512) {
        float v = xr[i];
        sum += v;
        int n = i >> 1;
        if (i & 1) imb[ldsmap(n)] = v;
        else       reb[ldsmap(n)] = v;
    }
    #pragma unroll
    for (int o = 32; o; o >>= 1) sum += __shfl_xor(sum, o);
    __syncthreads();
    if (lane == 0) redbuf[wv] = sum;
    __syncthreads();
    float tot = 0.f;
    #pragma unroll
    for (int i = 0; i < 8; ++i) tot += redbuf[i];
    const float mean = tot * (1.f / 20000.f);

    for (int n = tid; n < 10000; n += 512) {
        reb[ldsmap(n)] -= mean;
        imb[ldsmap(n)] -= mean;
    }
    __syncthreads();

    const float WR[5] = {1.f, 0.80901699437494745f, 0.30901699437494742f,
                         -0.30901699437494742f, -0.80901699437494745f};
    const float WI[5] = {0.f, -0.58778525229247312f, -0.95105651629515357f,
                         -0.95105651629515357f, -0.58778525229247312f};

    // 4 radix-10 DIF stages (in-place, output digit-reversed)
    #pragma unroll
    for (int s = 0; s < 4; ++s) {
        const int L  = (s == 0) ? 1000 : (s == 1) ? 100 : (s == 2) ? 10 : 1;
        const int sc = (s == 0) ? 1 : (s == 1) ? 10 : (s == 2) ? 100 : 1000;
        for (int w = tid; w < 1000; w += 512) {
            const int g = w / L;
            const int j = w - g * L;
            const int base = g * (10 * L) + j;
            float ar[10], ai[10];
            #pragma unroll
            for (int u = 0; u < 10; ++u) {
                int idx = ldsmap(base + u * L);
                ar[u] = reb[idx];
                ai[u] = imb[idx];
            }
            float Er[5], Ei[5], Or[5], Oi[5];
            dft5(ar[0], ai[0], ar[2], ai[2], ar[4], ai[4], ar[6], ai[6], ar[8], ai[8], Er, Ei);
            dft5(ar[1], ai[1], ar[3], ai[3], ar[5], ai[5], ar[7], ai[7], ar[9], ai[9], Or, Oi);
            #pragma unroll
            for (int k = 1; k < 5; ++k) {
                float tr = Or[k] * WR[k] - Oi[k] * WI[k];
                Oi[k] = Or[k] * WI[k] + Oi[k] * WR[k];
                Or[k] = tr;
            }
            const int jb = j * sc;
            #pragma unroll
            for (int k = 0; k < 5; ++k) {
                float xr0 = Er[k] + Or[k], xi0 = Ei[k] + Oi[k];
                float xr1 = Er[k] - Or[k], xi1 = Ei[k] - Oi[k];
                int i0 = ldsmap(base + k * L);
                int i1 = ldsmap(base + (k + 5) * L);
                if (k == 0) {
                    reb[i0] = xr0;
                    imb[i0] = xi0;
                } else {
                    float2 tw = gtw[jb * k];
                    reb[i0] = xr0 * tw.x - xi0 * tw.y;
                    imb[i0] = xr0 * tw.y + xi0 * tw.x;
                }
                float2 t5 = gtw[jb * (k + 5)];
                reb[i1] = xr1 * t5.x - xi1 * t5.y;
                imb[i1] = xr1 * t5.y + xi1 * t5.x;
            }
        }
        __syncthreads();
    }

    // real-FFT untangle + log1p|X|
    float harr[20];
    float sumsq = 0.f;
    unsigned short* hrow = hb + (size_t)b * 10240;
    #pragma unroll
    for (int i = 0; i < 20; ++i) {
        int k = tid + i * 512;
        float hval = 0.f;
        if (k <= 10000) {
            int k1 = (k == 10000) ? 0 : k;
            int k2 = (10000 - k) % 10000;
            int i1 = ldsmap(rev4(k1));
            int i2 = ldsmap(rev4(k2));
            float zr = reb[i1], zi = imb[i1];
            float wr = reb[i2], wi = imb[i2];
            float er = 0.5f * (zr + wr);
            float ei = 0.5f * (zi - wi);
            float odr = 0.5f * (zi + wi);
            float odi = -0.5f * (zr - wr);
            float2 tw = ut[k];
            float xre = er + tw.x * odr - tw.y * odi;
            float xim = ei + tw.x * odi + tw.y * odr;
            hval = log1pf(sqrtf(xre * xre + xim * xim));
        }
        harr[i] = hval;
        hrow[k] = f2bf(hval);
        sumsq += hval * hval;
    }
    #pragma unroll
    for (int o = 32; o; o >>= 1) sumsq += __shfl_xor(sumsq, o);
    __syncthreads();
    if (lane == 0) redbuf[wv] = sumsq;
    __syncthreads();
    float tsq = 0.f;
    #pragma unroll
    for (int i = 0; i < 8; ++i) tsq += redbuf[i];
    const float inv = 1.f / (sqrtf(tsq) + 1e-8f);

    unsigned short* crow = cb + (size_t)b * 10240;
    #pragma unroll
    for (int i = 0; i < 20; ++i) {
        int k = tid + i * 512;
        crow[k] = f2bf(harr[i] * harr[i] * inv);
    }
}

// ---------------------------------------------------------------------------
// Pack W0 -> bf16 padded; sigmoid(alpha0) -> bf16 padded (pads are zero).
// ---------------------------------------------------------------------------
__global__ __launch_bounds__(256)
void pack0_kernel(const float* __restrict__ W0, const float* __restrict__ A0,
                  unsigned short* __restrict__ Wb, unsigned short* __restrict__ Sb)
{
    int col = blockIdx.x * 256 + threadIdx.x;   // 0..10239
    int row = blockIdx.y;                        // 0..255
    if (blockIdx.z == 0) {
        float v = (col < 10001) ? W0[(size_t)row * 10001 + col] : 0.f;
        Wb[(size_t)row * 10240 + col] = f2bf(v);
    } else {
        float v = (col < 10001) ? 1.f / (1.f + expf(-A0[(size_t)row * 10001 + col])) : 0.f;
        Sb[(size_t)row * 10240 + col] = f2bf(v);
    }
}

// ---------------------------------------------------------------------------
// Transpose small weights to [d][h] fp32; apply sigmoid to alphas.
// ---------------------------------------------------------------------------
__global__ __launch_bounds__(256)
void pack_small_kernel(const float* __restrict__ W1, const float* __restrict__ A1,
                       const float* __restrict__ W2, const float* __restrict__ A2,
                       float* __restrict__ W1T, float* __restrict__ S1T,
                       float* __restrict__ W2T, float* __restrict__ S2T)
{
    int idx = blockIdx.x * 256 + threadIdx.x;
    if (idx < 32768) {
        int d = idx >> 7, h = idx & 127;
        W1T[idx] = W1[h * 256 + d];
    } else if (idx < 65536) {
        int o = idx - 32768;
        int d = o >> 7, h = o & 127;
        S1T[o] = 1.f / (1.f + expf(-A1[h * 256 + d]));
    } else if (idx < 73728) {
        int o = idx - 65536;
        int d = o >> 6, h = o & 63;
        W2T[o] = W2[h * 128 + d];
    } else if (idx < 81920) {
        int o = idx - 73728;
        int d = o >> 6, h = o & 63;
        S2T[o] = 1.f / (1.f + expf(-A2[h * 128 + d]));
    }
}

// ---------------------------------------------------------------------------
// Layer-0 dual GEMM (y = h*W0^T and p = c*S0^T), bf16 MFMA 16x16x32,
// BM=128 BN=64 BK=32, split-K=16 (640 each = 20 steps). grid (8,4,16) x 256.
// ---------------------------------------------------------------------------
__global__ __launch_bounds__(256)
void gemm0_kernel(const unsigned short* __restrict__ hb, const unsigned short* __restrict__ cb,
                  const unsigned short* __restrict__ Wb, const unsigned short* __restrict__ Sb,
                  float* __restrict__ Py, float* __restrict__ Pp)
{
    __shared__ unsigned short Ah[128 * 32];
    __shared__ unsigned short Ac[128 * 32];
    __shared__ unsigned short Bw[64 * 32];
    __shared__ unsigned short Bs[64 * 32];

    const int t = threadIdx.x;
    const int b0 = blockIdx.x * 128;
    const int n0 = blockIdx.y * 64;
    const int z = blockIdx.z;
    const int lane = t & 63;
    const int wv = t >> 6;
    const int ml = lane & 15;
    const int q8 = (lane >> 4) * 8;

    f32x4 accY[2][4], accP[2][4];
    #pragma unroll
    for (int mt = 0; mt < 2; ++mt)
        #pragma unroll
        for (int nt = 0; nt < 4; ++nt) {
            accY[mt][nt] = (f32x4){0.f, 0.f, 0.f, 0.f};
            accP[mt][nt] = (f32x4){0.f, 0.f, 0.f, 0.f};
        }

    const int ra = t >> 2;            // 0..63
    const int q = (t & 3) * 8;        // 0,8,16,24
    const int kbase = z * 640;

    for (int step = 0; step < 20; ++step) {
        const int k0 = kbase + step * 32;
        __syncthreads();   // LDS reuse guard
        {
            size_t ga = (size_t)(b0 + ra) * 10240 + k0 + q;
            *(int4*)&Ah[ra * 32 + q] = *(const int4*)&hb[ga];
            *(int4*)&Ac[ra * 32 + q] = *(const int4*)&cb[ga];
            size_t ga2 = (size_t)(b0 + ra + 64) * 10240 + k0 + q;
            *(int4*)&Ah[(ra + 64) * 32 + q] = *(const int4*)&hb[ga2];
            *(int4*)&Ac[(ra + 64) * 32 + q] = *(const int4*)&cb[ga2];
            size_t gb = (size_t)(n0 + ra) * 10240 + k0 + q;
            *(int4*)&Bw[ra * 32 + q] = *(const int4*)&Wb[gb];
            *(int4*)&Bs[ra * 32 + q] = *(const int4*)&Sb[gb];
        }
        __syncthreads();

        bf16x8 ah[2], ac[2], bw[4], bs[4];
        #pragma unroll
        for (int mt = 0; mt < 2; ++mt) {
            int mrow = wv * 32 + mt * 16 + ml;
            ah[mt] = *(const bf16x8*)&Ah[mrow * 32 + q8];
            ac[mt] = *(const bf16x8*)&Ac[mrow * 32 + q8];
        }
        #pragma unroll
        for (int nt = 0; nt < 4; ++nt) {
            int nrow = nt * 16 + ml;
            bw[nt] = *(const bf16x8*)&Bw[nrow * 32 + q8];
            bs[nt] = *(const bf16x8*)&Bs[nrow * 32 + q8];
        }
        #pragma unroll
        for (int mt = 0; mt < 2; ++mt)
            #pragma unroll
            for (int nt = 0; nt < 4; ++nt) {
                accY[mt][nt] = __builtin_amdgcn_mfma_f32_16x16x32_bf16(ah[mt], bw[nt], accY[mt][nt], 0, 0, 0);
                accP[mt][nt] = __builtin_amdgcn_mfma_f32_16x16x32_bf16(ac[mt], bs[nt], accP[mt][nt], 0, 0, 0);
            }
    }

    const int rq = (lane >> 4) * 4;
    #pragma unroll
    for (int mt = 0; mt < 2; ++mt)
        #pragma unroll
        for (int nt = 0; nt < 4; ++nt)
            #pragma unroll
            for (int r = 0; r < 4; ++r) {
                int m = b0 + wv * 32 + mt * 16 + rq + r;
                int n = n0 + nt * 16 + ml;
                size_t o = ((size_t)z * 1024 + m) * 256 + n;
                Py[o] = accY[mt][nt][r];
                Pp[o] = accP[mt][nt][r];
            }
}

// ---------------------------------------------------------------------------
// Combine splits + bias + plastic + LayerNorm(256) + GELU + c for next layer.
// ---------------------------------------------------------------------------
__global__ __launch_bounds__(256)
void combine0_kernel(const float* __restrict__ Py, const float* __restrict__ Pp,
                     const float* __restrict__ b0v, const float* __restrict__ eta0p,
                     const float* __restrict__ g0, const float* __restrict__ be0,
                     float* __restrict__ h1, float* __restrict__ c1)
{
    __shared__ float red[4];
    const int b = blockIdx.x;
    const int h = threadIdx.x;
    const int lane = h & 63;
    const int wv = h >> 6;

    float ys = 0.f, ps = 0.f;
    for (int s = 0; s < 16; ++s) {
        size_t o = ((size_t)s * 1024 + b) * 256 + h;
        ys += Py[o];
        ps += Pp[o];
    }
    float y = ys + b0v[h];
    float v = y + eta0p[0] * tanhf(y) * ps;

    float s1 = v;
    #pragma unroll
    for (int o = 32; o; o >>= 1) s1 += __shfl_xor(s1, o);
    __syncthreads();
    if (lane == 0) red[wv] = s1;
    __syncthreads();
    float sum = red[0] + red[1] + red[2] + red[3];

    float s2 = v * v;
    #pragma unroll
    for (int o = 32; o; o >>= 1) s2 += __shfl_xor(s2, o);
    __syncthreads();
    if (lane == 0) red[wv] = s2;
    __syncthreads();
    float sumsq = red[0] + red[1] + red[2] + red[3];

    float mu = sum * (1.f / 256.f);
    float var = sumsq * (1.f / 256.f) - mu * mu;
    float u = (v - mu) * rsqrtf(var + 1e-5f) * g0[h] + be0[h];
    float gl = gelu_f(u);

    float s3 = gl * gl;
    #pragma unroll
    for (int o = 32; o; o >>= 1) s3 += __shfl_xor(s3, o);
    __syncthreads();
    if (lane == 0) red[wv] = s3;
    __syncthreads();
    float gsq = red[0] + red[1] + red[2] + red[3];
    float inv = 1.f / (sqrtf(gsq) + 1e-8f);

    h1[(size_t)b * 256 + h] = gl;
    c1[(size_t)b * 256 + h] = gl * gl * inv;
}

// ---------------------------------------------------------------------------
// Tail: layers 1,2 + head, fp32. 8 rows per block. grid 128, block 256.
// ---------------------------------------------------------------------------
__global__ __launch_bounds__(256)
void tail_kernel(const float* __restrict__ h1, const float* __restrict__ c1,
                 const float* __restrict__ W1T, const float* __restrict__ S1T,
                 const float* __restrict__ b1, const float* __restrict__ eta1p,
                 const float* __restrict__ g1, const float* __restrict__ be1,
                 const float* __restrict__ W2T, const float* __restrict__ S2T,
                 const float* __restrict__ b2, const float* __restrict__ eta2p,
                 const float* __restrict__ g2, const float* __restrict__ be2,
                 const float* __restrict__ hw, const float* __restrict__ hbod,
                 float* __restrict__ out)
{
    __shared__ float sh[8][256];
    __shared__ float sc[8][256];
    __shared__ float sv[8][128];
    __shared__ float sh2[8][128];
    __shared__ float sc2[8][128];
    __shared__ float sv2[8][64];

    const int t = threadIdx.x;
    const int b0 = blockIdx.x * 8;
    const int lane = t & 63;
    const int wv = t >> 6;

    #pragma unroll
    for (int i = 0; i < 8; ++i) {
        int idx = t + i * 256;
        int r = idx >> 8, d = idx & 255;
        sh[r][d] = h1[(size_t)(b0 + r) * 256 + d];
        sc[r][d] = c1[(size_t)(b0 + r) * 256 + d];
    }
    __syncthreads();

    const int hcol = t & 127;
    const int r2 = t >> 7;
    float ya[4] = {0.f, 0.f, 0.f, 0.f};
    float pa[4] = {0.f, 0.f, 0.f, 0.f};
    for (int d = 0; d < 256; ++d) {
        float w = W1T[d * 128 + hcol];
        float s = S1T[d * 128 + hcol];
        #pragma unroll
        for (int i = 0; i < 4; ++i) {
            int r = r2 * 4 + i;
            ya[i] += sh[r][d] * w;
            pa[i] += sc[r][d] * s;
        }
    }
    const float e1 = eta1p[0];
    #pragma unroll
    for (int i = 0; i < 4; ++i) {
        int r = r2 * 4 + i;
        float y = ya[i] + b1[hcol];
        sv[r][hcol] = y + e1 * tanhf(y) * pa[i];
    }
    __syncthreads();

    #pragma unroll
    for (int rr = 0; rr < 2; ++rr) {
        int r = wv * 2 + rr;
        float v0 = sv[r][lane];
        float v1 = sv[r][lane + 64];
        float s = v0 + v1, sq = v0 * v0 + v1 * v1;
        #pragma unroll
        for (int o = 32; o; o >>= 1) { s += __shfl_xor(s, o); sq += __shfl_xor(sq, o); }
        float mu = s * (1.f / 128.f);
        float var = sq * (1.f / 128.f) - mu * mu;
        float rs = rsqrtf(var + 1e-5f);
        float u0 = (v0 - mu) * rs * g1[lane] + be1[lane];
        float u1 = (v1 - mu) * rs * g1[lane + 64] + be1[lane + 64];
        float ge0 = gelu_f(u0);
        float ge1 = gelu_f(u1);
        float gsq = ge0 * ge0 + ge1 * ge1;
        #pragma unroll
        for (int o = 32; o; o >>= 1) gsq += __shfl_xor(gsq, o);
        float inv = 1.f / (sqrtf(gsq) + 1e-8f);
        sh2[r][lane] = ge0; sh2[r][lane + 64] = ge1;
        sc2[r][lane] = ge0 * ge0 * inv; sc2[r][lane + 64] = ge1 * ge1 * inv;
    }
    __syncthreads();

    const int h2c = t & 63;
    const int r4 = t >> 6;
    float yb[2] = {0.f, 0.f};
    float pb[2] = {0.f, 0.f};
    for (int d = 0; d < 128; ++d) {
        float w = W2T[d * 64 + h2c];
        float s = S2T[d * 64 + h2c];
        #pragma unroll
        for (int i = 0; i < 2; ++i) {
            int r = r4 * 2 + i;
            yb[i] += sh2[r][d] * w;
            pb[i] += sc2[r][d] * s;
        }
    }
    const float e2 = eta2p[0];
    #pragma unroll
    for (int i = 0; i < 2; ++i) {
        int r = r4 * 2 + i;
        float y = yb[i] + b2[h2c];
        sv2[r][h2c] = y + e2 * tanhf(y) * pb[i];
    }
    __syncthreads();

    #pragma unroll
    for (int rr = 0; rr < 2; ++rr) {
        int r = wv * 2 + rr;
        float v0 = sv2[r][lane];
        float s = v0, sq = v0 * v0;
        #pragma unroll
        for (int o = 32; o; o >>= 1) { s += __shfl_xor(s, o); sq += __shfl_xor(sq, o); }
        float mu = s * (1.f / 64.f);
        float var = sq * (1.f / 64.f) - mu * mu;
        float rs = rsqrtf(var + 1e-5f);
        float u = (v0 - mu) * rs * g2[lane] + be2[lane];
        float g = gelu_f(u);
        float hc = g * hw[lane];
        #pragma unroll
        for (int o = 32; o; o >>= 1) hc += __shfl_xor(hc, o);
        if (lane == 0) out[b0 + r] = hc + hbod[0];
    }
}

// ---------------------------------------------------------------------------
extern "C" void kernel_launch(void* const* d_in, const int* in_sizes, int n_in,
                              void* d_out, int out_size, void* d_ws, size_t ws_size,
                              hipStream_t stream)
{
    const float* x    = (const float*)d_in[0];
    const float* W0   = (const float*)d_in[1];
    const float* A0   = (const float*)d_in[2];
    const float* b0   = (const float*)d_in[3];
    const float* eta0 = (const float*)d_in[4];
    const float* g0   = (const float*)d_in[5];
    const float* be0  = (const float*)d_in[6];
    const float* W1   = (const float*)d_in[7];
    const float* A1   = (const float*)d_in[8];
    const float* b1   = (const float*)d_in[9];
    const float* eta1 = (const float*)d_in[10];
    const float* g1   = (const float*)d_in[11];
    const float* be1  = (const float*)d_in[12];
    const float* W2   = (const float*)d_in[13];
    const float* A2   = (const float*)d_in[14];
    const float* b2   = (const float*)d_in[15];
    const float* eta2 = (const float*)d_in[16];
    const float* g2   = (const float*)d_in[17];
    const float* be2  = (const float*)d_in[18];
    const float* hw   = (const float*)d_in[19];
    const float* hbod = (const float*)d_in[20];
    float* out = (float*)d_out;

    char* w = (char*)d_ws;
    unsigned short* hb  = (unsigned short*)(w + 0);          // 20971520
    unsigned short* cb  = (unsigned short*)(w + 20971520);   // 20971520
    unsigned short* Wb0 = (unsigned short*)(w + 41943040);   // 5242880
    unsigned short* Sb0 = (unsigned short*)(w + 47185920);   // 5242880
    float* Py  = (float*)(w + 52428800);                     // 16777216
    float* Pp  = (float*)(w + 69206016);                     // 16777216
    float* h1  = (float*)(w + 85983232);                     // 1048576
    float* c1  = (float*)(w + 87031808);                     // 1048576
    float* W1T = (float*)(w + 88080384);                     // 131072
    float* S1T = (float*)(w + 88211456);                     // 131072
    float* W2T = (float*)(w + 88342528);                     // 32768
    float* S2T = (float*)(w + 88375296);                     // 32768
    // Twiddle tables alias the head of Py: fft reads them BEFORE gemm0 writes
    // Py (stream-ordered), so no extra workspace is needed.
    float2* gtw = (float2*)(w + 52428800);                   // 80000 B
    float2* ut  = (float2*)(w + 52508800);                   // 81928 B

    hipLaunchKernelGGL(twid_init, dim3(41), dim3(256), 0, stream, gtw, ut);
    hipLaunchKernelGGL(fft_kernel, dim3(1024), dim3(512), 0, stream, x, gtw, ut, hb, cb);
    hipLaunchKernelGGL(pack0_kernel, dim3(40, 256, 2), dim3(256), 0, stream, W0, A0, Wb0, Sb0);
    hipLaunchKernelGGL(pack_small_kernel, dim3(320), dim3(256), 0, stream, W1, A1, W2, A2, W1T, S1T, W2T, S2T);
    hipLaunchKernelGGL(gemm0_kernel, dim3(8, 4, 16), dim3(256), 0, stream, hb, cb, Wb0, Sb0, Py, Pp);
    hipLaunchKernelGGL(combine0_kernel, dim3(1024), dim3(256), 0, stream, Py, Pp, b0, eta0, g0, be0, h1, c1);
    hipLaunchKernelGGL(tail_kernel, dim3(128), dim3(256), 0, stream, h1, c1, W1T, S1T, b1, eta1, g1, be1,
                       W2T, S2T, b2, eta2, g2, be2, hw, hbod, out);
}

// Round 3
// 342.797 us; speedup vs baseline: 1.2453x; 1.0274x over previous
//
#include <hip/hip_runtime.h>
#include <hip/hip_bf16.h>
#include <math.h>

typedef short bf16x8 __attribute__((ext_vector_type(8)));
typedef float f32x4 __attribute__((ext_vector_type(4)));

static __device__ __forceinline__ unsigned short f2bf(float f) {
    unsigned int u = __float_as_uint(f);
    unsigned int r = (u + 0x7fffu + ((u >> 16) & 1u)) >> 16;
    return (unsigned short)r;
}

static __device__ __forceinline__ float gelu_f(float x) {
    return 0.5f * x * (1.f + erff(x * 0.70710678118654752f));
}

// async global->LDS, 16B per lane; LDS dest is wave-uniform base + lane*16
static __device__ __forceinline__ void gload_lds16(const void* g, void* l) {
    __builtin_amdgcn_global_load_lds(
        (const __attribute__((address_space(1))) unsigned int*)g,
        (__attribute__((address_space(3))) unsigned int*)l, 16, 0, 0);
}

// LDS index skew for FFT buffers
static __device__ __forceinline__ int ldsmap(int i) { return i + (i >> 6); }

static __device__ __forceinline__ int rev4(int k) {
    int d0 = k % 10; k /= 10;
    int d1 = k % 10; k /= 10;
    int d2 = k % 10; int d3 = k / 10;
    return d0 * 1000 + d1 * 100 + d2 * 10 + d3;
}

// forward 5-point DFT (W5 = e^{-2pi i/5}), Winograd-style
static __device__ __forceinline__ void dft5(
    float a0r, float a0i, float a1r, float a1i, float a2r, float a2i,
    float a3r, float a3i, float a4r, float a4i,
    float* Xr, float* Xi)
{
    const float c1 = 0.30901699437494742f, c2 = -0.80901699437494745f;
    const float s1 = 0.95105651629515357f, s2 = 0.58778525229247312f;
    float t1r = a1r + a4r, t1i = a1i + a4i;
    float d1r = a1r - a4r, d1i = a1i - a4i;
    float t2r = a2r + a3r, t2i = a2i + a3i;
    float d2r = a2r - a3r, d2i = a2i - a3i;
    Xr[0] = a0r + t1r + t2r; Xi[0] = a0i + t1i + t2i;
    float m1r = a0r + c1 * t1r + c2 * t2r, m1i = a0i + c1 * t1i + c2 * t2i;
    float m2r = a0r + c2 * t1r + c1 * t2r, m2i = a0i + c2 * t1i + c1 * t2i;
    float n1r = s1 * d1r + s2 * d2r, n1i = s1 * d1i + s2 * d2i;
    float n2r = s2 * d1r - s1 * d2r, n2i = s2 * d1i - s1 * d2i;
    Xr[1] = m1r + n1i; Xi[1] = m1i - n1r;
    Xr[4] = m1r - n1i; Xi[4] = m1i + n1r;
    Xr[2] = m2r + n2i; Xi[2] = m2i - n2r;
    Xr[3] = m2r - n2i; Xi[3] = m2i + n2r;
}

// ---------------------------------------------------------------------------
// Twiddle tables: gtw[m] = e^{-2pi i m/10000}, ut[k] = e^{-i pi k/10000}
// ---------------------------------------------------------------------------
__global__ __launch_bounds__(256)
void twid_init(float2* __restrict__ gtw, float2* __restrict__ ut)
{
    int i = blockIdx.x * 256 + threadIdx.x;
    if (i < 10000) {
        float ph = -6.28318530717958648f * (float)i * (1.f / 10000.f);
        float s, c; sincosf(ph, &s, &c);
        gtw[i] = make_float2(c, s);
    }
    if (i < 10241) {
        float ph = -3.14159265358979324f * (float)i * (1.f / 10000.f);
        float s, c; sincosf(ph, &s, &c);
        ut[i] = make_float2(c, s);
    }
}

// ---------------------------------------------------------------------------
// FFT kernel (unchanged from R2): one block per batch row.
// ---------------------------------------------------------------------------
__global__ __launch_bounds__(512, 4)
void fft_kernel(const float* __restrict__ x,
                const float2* __restrict__ gtw,
                const float2* __restrict__ ut,
                unsigned short* __restrict__ hb,
                unsigned short* __restrict__ cb)
{
    __shared__ float reb[10156];
    __shared__ float imb[10156];
    __shared__ float redbuf[8];

    const int b = blockIdx.x;
    const int tid = threadIdx.x;
    const int lane = tid & 63;
    const int wv = tid >> 6;
    const float* xr = x + (size_t)b * 20000;

    float sum = 0.f;
    for (int i = tid; i < 20000; i += 512) {
        float v = xr[i];
        sum += v;
        int n = i >> 1;
        if (i & 1) imb[ldsmap(n)] = v;
        else       reb[ldsmap(n)] = v;
    }
    #pragma unroll
    for (int o = 32; o; o >>= 1) sum += __shfl_xor(sum, o);
    __syncthreads();
    if (lane == 0) redbuf[wv] = sum;
    __syncthreads();
    float tot = 0.f;
    #pragma unroll
    for (int i = 0; i < 8; ++i) tot += redbuf[i];
    const float mean = tot * (1.f / 20000.f);

    for (int n = tid; n < 10000; n += 512) {
        reb[ldsmap(n)] -= mean;
        imb[ldsmap(n)] -= mean;
    }
    __syncthreads();

    const float WR[5] = {1.f, 0.80901699437494745f, 0.30901699437494742f,
                         -0.30901699437494742f, -0.80901699437494745f};
    const float WI[5] = {0.f, -0.58778525229247312f, -0.95105651629515357f,
                         -0.95105651629515357f, -0.58778525229247312f};

    #pragma unroll
    for (int s = 0; s < 4; ++s) {
        const int L  = (s == 0) ? 1000 : (s == 1) ? 100 : (s == 2) ? 10 : 1;
        const int sc = (s == 0) ? 1 : (s == 1) ? 10 : (s == 2) ? 100 : 1000;
        for (int w = tid; w < 1000; w += 512) {
            const int g = w / L;
            const int j = w - g * L;
            const int base = g * (10 * L) + j;
            float ar[10], ai[10];
            #pragma unroll
            for (int u = 0; u < 10; ++u) {
                int idx = ldsmap(base + u * L);
                ar[u] = reb[idx];
                ai[u] = imb[idx];
            }
            float Er[5], Ei[5], Or[5], Oi[5];
            dft5(ar[0], ai[0], ar[2], ai[2], ar[4], ai[4], ar[6], ai[6], ar[8], ai[8], Er, Ei);
            dft5(ar[1], ai[1], ar[3], ai[3], ar[5], ai[5], ar[7], ai[7], ar[9], ai[9], Or, Oi);
            #pragma unroll
            for (int k = 1; k < 5; ++k) {
                float tr = Or[k] * WR[k] - Oi[k] * WI[k];
                Oi[k] = Or[k] * WI[k] + Oi[k] * WR[k];
                Or[k] = tr;
            }
            const int jb = j * sc;
            #pragma unroll
            for (int k = 0; k < 5; ++k) {
                float xr0 = Er[k] + Or[k], xi0 = Ei[k] + Oi[k];
                float xr1 = Er[k] - Or[k], xi1 = Ei[k] - Oi[k];
                int i0 = ldsmap(base + k * L);
                int i1 = ldsmap(base + (k + 5) * L);
                if (k == 0) {
                    reb[i0] = xr0;
                    imb[i0] = xi0;
                } else {
                    float2 tw = gtw[jb * k];
                    reb[i0] = xr0 * tw.x - xi0 * tw.y;
                    imb[i0] = xr0 * tw.y + xi0 * tw.x;
                }
                float2 t5 = gtw[jb * (k + 5)];
                reb[i1] = xr1 * t5.x - xi1 * t5.y;
                imb[i1] = xr1 * t5.y + xi1 * t5.x;
            }
        }
        __syncthreads();
    }

    float harr[20];
    float sumsq = 0.f;
    unsigned short* hrow = hb + (size_t)b * 10240;
    #pragma unroll
    for (int i = 0; i < 20; ++i) {
        int k = tid + i * 512;
        float hval = 0.f;
        if (k <= 10000) {
            int k1 = (k == 10000) ? 0 : k;
            int k2 = (10000 - k) % 10000;
            int i1 = ldsmap(rev4(k1));
            int i2 = ldsmap(rev4(k2));
            float zr = reb[i1], zi = imb[i1];
            float wr = reb[i2], wi = imb[i2];
            float er = 0.5f * (zr + wr);
            float ei = 0.5f * (zi - wi);
            float odr = 0.5f * (zi + wi);
            float odi = -0.5f * (zr - wr);
            float2 tw = ut[k];
            float xre = er + tw.x * odr - tw.y * odi;
            float xim = ei + tw.x * odi + tw.y * odr;
            hval = log1pf(sqrtf(xre * xre + xim * xim));
        }
        harr[i] = hval;
        hrow[k] = f2bf(hval);
        sumsq += hval * hval;
    }
    #pragma unroll
    for (int o = 32; o; o >>= 1) sumsq += __shfl_xor(sumsq, o);
    __syncthreads();
    if (lane == 0) redbuf[wv] = sumsq;
    __syncthreads();
    float tsq = 0.f;
    #pragma unroll
    for (int i = 0; i < 8; ++i) tsq += redbuf[i];
    const float inv = 1.f / (sqrtf(tsq) + 1e-8f);

    unsigned short* crow = cb + (size_t)b * 10240;
    #pragma unroll
    for (int i = 0; i < 20; ++i) {
        int k = tid + i * 512;
        crow[k] = f2bf(harr[i] * harr[i] * inv);
    }
}

// ---------------------------------------------------------------------------
// Vectorized pack: W0 / sigmoid(alpha0) -> bf16 (cols 0..10000).
// Flat float4 reads: 256*10001 = 2560256 = 4*640064 exactly. grid (2501, 2).
// ---------------------------------------------------------------------------
__global__ __launch_bounds__(256)
void pack0_kernel(const float* __restrict__ W0, const float* __restrict__ A0,
                  unsigned short* __restrict__ Wb, unsigned short* __restrict__ Sb)
{
    int f4 = blockIdx.x * 256 + threadIdx.x;
    if (f4 >= 640064) return;
    const bool isW = (blockIdx.y == 0);
    const float* src = isW ? W0 : A0;
    unsigned short* dst = isW ? Wb : Sb;
    float4 v = ((const float4*)src)[f4];
    float e[4] = {v.x, v.y, v.z, v.w};
    int flat = f4 * 4;
    int row = flat / 10001;
    int col = flat - row * 10001;
    #pragma unroll
    for (int i = 0; i < 4; ++i) {
        if (col == 10001) { row++; col = 0; }
        float val = isW ? e[i] : 1.f / (1.f + expf(-e[i]));
        dst[(size_t)row * 10240 + col] = f2bf(val);
        col++;
    }
}

// zero the K-pad columns 10001..10239 of Wb/Sb (re-poisoned every call)
__global__ __launch_bounds__(256)
void pad0_kernel(unsigned short* __restrict__ Wb, unsigned short* __restrict__ Sb)
{
    int i = blockIdx.x * 256 + threadIdx.x;   // 256*239 = 61184
    if (i >= 61184) return;
    int row = i / 239;
    int col = 10001 + (i - row * 239);
    Wb[(size_t)row * 10240 + col] = 0;
    Sb[(size_t)row * 10240 + col] = 0;
}

// ---------------------------------------------------------------------------
// Transpose small weights to [d][h] fp32; apply sigmoid to alphas.
// ---------------------------------------------------------------------------
__global__ __launch_bounds__(256)
void pack_small_kernel(const float* __restrict__ W1, const float* __restrict__ A1,
                       const float* __restrict__ W2, const float* __restrict__ A2,
                       float* __restrict__ W1T, float* __restrict__ S1T,
                       float* __restrict__ W2T, float* __restrict__ S2T)
{
    int idx = blockIdx.x * 256 + threadIdx.x;
    if (idx < 32768) {
        int d = idx >> 7, h = idx & 127;
        W1T[idx] = W1[h * 256 + d];
    } else if (idx < 65536) {
        int o = idx - 32768;
        int d = o >> 7, h = o & 127;
        S1T[o] = 1.f / (1.f + expf(-A1[h * 256 + d]));
    } else if (idx < 73728) {
        int o = idx - 65536;
        int d = o >> 6, h = o & 63;
        W2T[o] = W2[h * 128 + d];
    } else if (idx < 81920) {
        int o = idx - 73728;
        int d = o >> 6, h = o & 63;
        S2T[o] = 1.f / (1.f + expf(-A2[h * 128 + d]));
    }
}

// ---------------------------------------------------------------------------
// Layer-0 dual GEMM, m97-style: BM=128 BN=64 BK=64, split-K=16 (10 steps),
// global_load_lds 16B staging with XOR k-chunk swizzle. grid (8,4,16) x 256.
// LDS 48KB -> 2 blocks/CU.
// ---------------------------------------------------------------------------
__global__ __launch_bounds__(256, 2)
void gemm0_kernel(const unsigned short* __restrict__ hb, const unsigned short* __restrict__ cb,
                  const unsigned short* __restrict__ Wb, const unsigned short* __restrict__ Sb,
                  float* __restrict__ Py, float* __restrict__ Pp)
{
    __shared__ unsigned short Ah[128 * 64];
    __shared__ unsigned short Ac[128 * 64];
    __shared__ unsigned short Bw[64 * 64];
    __shared__ unsigned short Bs[64 * 64];

    const int t = threadIdx.x;
    const int b0 = blockIdx.x * 128;
    const int n0 = blockIdx.y * 64;
    const int z = blockIdx.z;
    const int lane = t & 63;
    const int wv = t >> 6;
    const int ml = lane & 15;
    const int q4 = lane >> 4;             // 0..3
    const int s0 = q4 ^ (ml & 7);         // base swizzle slot

    // staging lane decomposition: 8 rows x 8 slots per 1KB chunk
    const int sub = lane >> 3;            // row within chunk
    const int sl = lane & 7;              // slot within chunk
    const int gsw = sl ^ sub;             // swizzled source k-chunk

    f32x4 accY[2][4], accP[2][4];
    #pragma unroll
    for (int mt = 0; mt < 2; ++mt)
        #pragma unroll
        for (int nt = 0; nt < 4; ++nt) {
            accY[mt][nt] = (f32x4){0.f, 0.f, 0.f, 0.f};
            accP[mt][nt] = (f32x4){0.f, 0.f, 0.f, 0.f};
        }

    const int kbase = z * 640;

    for (int step = 0; step < 10; ++step) {
        const int k0 = kbase + step * 64;
        __syncthreads();   // LDS reuse guard
        // A tiles: 16 chunks each; wave wv stages chunks wv*4+j
        #pragma unroll
        for (int j = 0; j < 4; ++j) {
            const int c = wv * 4 + j;
            const size_t go = (size_t)(b0 + c * 8 + sub) * 10240 + k0 + gsw * 8;
            gload_lds16(&hb[go], &Ah[c * 512]);
            gload_lds16(&cb[go], &Ac[c * 512]);
        }
        // B tiles: 8 chunks each; wave wv stages chunks wv*2+j
        #pragma unroll
        for (int j = 0; j < 2; ++j) {
            const int c = wv * 2 + j;
            const size_t go = (size_t)(n0 + c * 8 + sub) * 10240 + k0 + gsw * 8;
            gload_lds16(&Wb[go], &Bw[c * 512]);
            gload_lds16(&Sb[go], &Bs[c * 512]);
        }
        __syncthreads();

        #pragma unroll
        for (int kk = 0; kk < 2; ++kk) {
            const int slot = (s0 ^ (kk << 2)) << 3;
            bf16x8 ah[2], ac[2], bw[4], bs[4];
            #pragma unroll
            for (int mt = 0; mt < 2; ++mt) {
                int mrow = wv * 32 + mt * 16 + ml;
                ah[mt] = *(const bf16x8*)&Ah[mrow * 64 + slot];
                ac[mt] = *(const bf16x8*)&Ac[mrow * 64 + slot];
            }
            #pragma unroll
            for (int nt = 0; nt < 4; ++nt) {
                int nrow = nt * 16 + ml;
                bw[nt] = *(const bf16x8*)&Bw[nrow * 64 + slot];
                bs[nt] = *(const bf16x8*)&Bs[nrow * 64 + slot];
            }
            #pragma unroll
            for (int mt = 0; mt < 2; ++mt)
                #pragma unroll
                for (int nt = 0; nt < 4; ++nt) {
                    accY[mt][nt] = __builtin_amdgcn_mfma_f32_16x16x32_bf16(ah[mt], bw[nt], accY[mt][nt], 0, 0, 0);
                    accP[mt][nt] = __builtin_amdgcn_mfma_f32_16x16x32_bf16(ac[mt], bs[nt], accP[mt][nt], 0, 0, 0);
                }
        }
    }

    const int rq = q4 * 4;
    #pragma unroll
    for (int mt = 0; mt < 2; ++mt)
        #pragma unroll
        for (int nt = 0; nt < 4; ++nt)
            #pragma unroll
            for (int r = 0; r < 4; ++r) {
                int m = b0 + wv * 32 + mt * 16 + rq + r;
                int n = n0 + nt * 16 + ml;
                size_t o = ((size_t)z * 1024 + m) * 256 + n;
                Py[o] = accY[mt][nt][r];
                Pp[o] = accP[mt][nt][r];
            }
}

// ---------------------------------------------------------------------------
// Combine splits + bias + plastic + LayerNorm(256) + GELU + c for next layer.
// ---------------------------------------------------------------------------
__global__ __launch_bounds__(256)
void combine0_kernel(const float* __restrict__ Py, const float* __restrict__ Pp,
                     const float* __restrict__ b0v, const float* __restrict__ eta0p,
                     const float* __restrict__ g0, const float* __restrict__ be0,
                     float* __restrict__ h1, float* __restrict__ c1)
{
    __shared__ float red[4];
    const int b = blockIdx.x;
    const int h = threadIdx.x;
    const int lane = h & 63;
    const int wv = h >> 6;

    float ys = 0.f, ps = 0.f;
    for (int s = 0; s < 16; ++s) {
        size_t o = ((size_t)s * 1024 + b) * 256 + h;
        ys += Py[o];
        ps += Pp[o];
    }
    float y = ys + b0v[h];
    float v = y + eta0p[0] * tanhf(y) * ps;

    float s1 = v;
    #pragma unroll
    for (int o = 32; o; o >>= 1) s1 += __shfl_xor(s1, o);
    __syncthreads();
    if (lane == 0) red[wv] = s1;
    __syncthreads();
    float sum = red[0] + red[1] + red[2] + red[3];

    float s2 = v * v;
    #pragma unroll
    for (int o = 32; o; o >>= 1) s2 += __shfl_xor(s2, o);
    __syncthreads();
    if (lane == 0) red[wv] = s2;
    __syncthreads();
    float sumsq = red[0] + red[1] + red[2] + red[3];

    float mu = sum * (1.f / 256.f);
    float var = sumsq * (1.f / 256.f) - mu * mu;
    float u = (v - mu) * rsqrtf(var + 1e-5f) * g0[h] + be0[h];
    float gl = gelu_f(u);

    float s3 = gl * gl;
    #pragma unroll
    for (int o = 32; o; o >>= 1) s3 += __shfl_xor(s3, o);
    __syncthreads();
    if (lane == 0) red[wv] = s3;
    __syncthreads();
    float gsq = red[0] + red[1] + red[2] + red[3];
    float inv = 1.f / (sqrtf(gsq) + 1e-8f);

    h1[(size_t)b * 256 + h] = gl;
    c1[(size_t)b * 256 + h] = gl * gl * inv;
}

// ---------------------------------------------------------------------------
// Tail: layers 1,2 + head, fp32. 8 rows per block. grid 128, block 256.
// ---------------------------------------------------------------------------
__global__ __launch_bounds__(256)
void tail_kernel(const float* __restrict__ h1, const float* __restrict__ c1,
                 const float* __restrict__ W1T, const float* __restrict__ S1T,
                 const float* __restrict__ b1, const float* __restrict__ eta1p,
                 const float* __restrict__ g1, const float* __restrict__ be1,
                 const float* __restrict__ W2T, const float* __restrict__ S2T,
                 const float* __restrict__ b2, const float* __restrict__ eta2p,
                 const float* __restrict__ g2, const float* __restrict__ be2,
                 const float* __restrict__ hw, const float* __restrict__ hbod,
                 float* __restrict__ out)
{
    __shared__ float sh[8][256];
    __shared__ float sc[8][256];
    __shared__ float sv[8][128];
    __shared__ float sh2[8][128];
    __shared__ float sc2[8][128];
    __shared__ float sv2[8][64];

    const int t = threadIdx.x;
    const int b0 = blockIdx.x * 8;
    const int lane = t & 63;
    const int wv = t >> 6;

    #pragma unroll
    for (int i = 0; i < 8; ++i) {
        int idx = t + i * 256;
        int r = idx >> 8, d = idx & 255;
        sh[r][d] = h1[(size_t)(b0 + r) * 256 + d];
        sc[r][d] = c1[(size_t)(b0 + r) * 256 + d];
    }
    __syncthreads();

    const int hcol = t & 127;
    const int r2 = t >> 7;
    float ya[4] = {0.f, 0.f, 0.f, 0.f};
    float pa[4] = {0.f, 0.f, 0.f, 0.f};
    for (int d = 0; d < 256; ++d) {
        float w = W1T[d * 128 + hcol];
        float s = S1T[d * 128 + hcol];
        #pragma unroll
        for (int i = 0; i < 4; ++i) {
            int r = r2 * 4 + i;
            ya[i] += sh[r][d] * w;
            pa[i] += sc[r][d] * s;
        }
    }
    const float e1 = eta1p[0];
    #pragma unroll
    for (int i = 0; i < 4; ++i) {
        int r = r2 * 4 + i;
        float y = ya[i] + b1[hcol];
        sv[r][hcol] = y + e1 * tanhf(y) * pa[i];
    }
    __syncthreads();

    #pragma unroll
    for (int rr = 0; rr < 2; ++rr) {
        int r = wv * 2 + rr;
        float v0 = sv[r][lane];
        float v1 = sv[r][lane + 64];
        float s = v0 + v1, sq = v0 * v0 + v1 * v1;
        #pragma unroll
        for (int o = 32; o; o >>= 1) { s += __shfl_xor(s, o); sq += __shfl_xor(sq, o); }
        float mu = s * (1.f / 128.f);
        float var = sq * (1.f / 128.f) - mu * mu;
        float rs = rsqrtf(var + 1e-5f);
        float u0 = (v0 - mu) * rs * g1[lane] + be1[lane];
        float u1 = (v1 - mu) * rs * g1[lane + 64] + be1[lane + 64];
        float ge0 = gelu_f(u0);
        float ge1 = gelu_f(u1);
        float gsq = ge0 * ge0 + ge1 * ge1;
        #pragma unroll
        for (int o = 32; o; o >>= 1) gsq += __shfl_xor(gsq, o);
        float inv = 1.f / (sqrtf(gsq) + 1e-8f);
        sh2[r][lane] = ge0; sh2[r][lane + 64] = ge1;
        sc2[r][lane] = ge0 * ge0 * inv; sc2[r][lane + 64] = ge1 * ge1 * inv;
    }
    __syncthreads();

    const int h2c = t & 63;
    const int r4 = t >> 6;
    float yb[2] = {0.f, 0.f};
    float pb[2] = {0.f, 0.f};
    for (int d = 0; d < 128; ++d) {
        float w = W2T[d * 64 + h2c];
        float s = S2T[d * 64 + h2c];
        #pragma unroll
        for (int i = 0; i < 2; ++i) {
            int r = r4 * 2 + i;
            yb[i] += sh2[r][d] * w;
            pb[i] += sc2[r][d] * s;
        }
    }
    const float e2 = eta2p[0];
    #pragma unroll
    for (int i = 0; i < 2; ++i) {
        int r = r4 * 2 + i;
        float y = yb[i] + b2[h2c];
        sv2[r][h2c] = y + e2 * tanhf(y) * pb[i];
    }
    __syncthreads();

    #pragma unroll
    for (int rr = 0; rr < 2; ++rr) {
        int r = wv * 2 + rr;
        float v0 = sv2[r][lane];
        float s = v0, sq = v0 * v0;
        #pragma unroll
        for (int o = 32; o; o >>= 1) { s += __shfl_xor(s, o); sq += __shfl_xor(sq, o); }
        float mu = s * (1.f / 64.f);
        float var = sq * (1.f / 64.f) - mu * mu;
        float rs = rsqrtf(var + 1e-5f);
        float u = (v0 - mu) * rs * g2[lane] + be2[lane];
        float g = gelu_f(u);
        float hc = g * hw[lane];
        #pragma unroll
        for (int o = 32; o; o >>= 1) hc += __shfl_xor(hc, o);
        if (lane == 0) out[b0 + r] = hc + hbod[0];
    }
}

// ---------------------------------------------------------------------------
extern "C" void kernel_launch(void* const* d_in, const int* in_sizes, int n_in,
                              void* d_out, int out_size, void* d_ws, size_t ws_size,
                              hipStream_t stream)
{
    const float* x    = (const float*)d_in[0];
    const float* W0   = (const float*)d_in[1];
    const float* A0   = (const float*)d_in[2];
    const float* b0   = (const float*)d_in[3];
    const float* eta0 = (const float*)d_in[4];
    const float* g0   = (const float*)d_in[5];
    const float* be0  = (const float*)d_in[6];
    const float* W1   = (const float*)d_in[7];
    const float* A1   = (const float*)d_in[8];
    const float* b1   = (const float*)d_in[9];
    const float* eta1 = (const float*)d_in[10];
    const float* g1   = (const float*)d_in[11];
    const float* be1  = (const float*)d_in[12];
    const float* W2   = (const float*)d_in[13];
    const float* A2   = (const float*)d_in[14];
    const float* b2   = (const float*)d_in[15];
    const float* eta2 = (const float*)d_in[16];
    const float* g2   = (const float*)d_in[17];
    const float* be2  = (const float*)d_in[18];
    const float* hw   = (const float*)d_in[19];
    const float* hbod = (const float*)d_in[20];
    float* out = (float*)d_out;

    char* w = (char*)d_ws;
    unsigned short* hb  = (unsigned short*)(w + 0);          // 20971520
    unsigned short* cb  = (unsigned short*)(w + 20971520);   // 20971520
    unsigned short* Wb0 = (unsigned short*)(w + 41943040);   // 5242880
    unsigned short* Sb0 = (unsigned short*)(w + 47185920);   // 5242880
    float* Py  = (float*)(w + 52428800);                     // 16777216
    float* Pp  = (float*)(w + 69206016);                     // 16777216
    float* h1  = (float*)(w + 85983232);                     // 1048576
    float* c1  = (float*)(w + 87031808);                     // 1048576
    float* W1T = (float*)(w + 88080384);                     // 131072
    float* S1T = (float*)(w + 88211456);                     // 131072
    float* W2T = (float*)(w + 88342528);                     // 32768
    float* S2T = (float*)(w + 88375296);                     // 32768
    // Twiddle tables alias head of Py (read by fft before gemm0 writes Py).
    float2* gtw = (float2*)(w + 52428800);
    float2* ut  = (float2*)(w + 52508800);

    hipLaunchKernelGGL(twid_init, dim3(41), dim3(256), 0, stream, gtw, ut);
    hipLaunchKernelGGL(fft_kernel, dim3(1024), dim3(512), 0, stream, x, gtw, ut, hb, cb);
    hipLaunchKernelGGL(pack0_kernel, dim3(2501, 2), dim3(256), 0, stream, W0, A0, Wb0, Sb0);
    hipLaunchKernelGGL(pad0_kernel, dim3(240), dim3(256), 0, stream, Wb0, Sb0);
    hipLaunchKernelGGL(pack_small_kernel, dim3(320), dim3(256), 0, stream, W1, A1, W2, A2, W1T, S1T, W2T, S2T);
    hipLaunchKernelGGL(gemm0_kernel, dim3(8, 4, 16), dim3(256), 0, stream, hb, cb, Wb0, Sb0, Py, Pp);
    hipLaunchKernelGGL(combine0_kernel, dim3(1024), dim3(256), 0, stream, Py, Pp, b0, eta0, g0, be0, h1, c1);
    hipLaunchKernelGGL(tail_kernel, dim3(128), dim3(256), 0, stream, h1, c1, W1T, S1T, b1, eta1, g1, be1,
                       W2T, S2T, b2, eta2, g2, be2, hw, hbod, out);
}

// Round 4
// 295.687 us; speedup vs baseline: 1.4437x; 1.1593x over previous
//
#include <hip/hip_runtime.h>
#include <hip/hip_bf16.h>
#include <math.h>

typedef short bf16x8 __attribute__((ext_vector_type(8)));
typedef float f32x4 __attribute__((ext_vector_type(4)));

static __device__ __forceinline__ unsigned short f2bf(float f) {
    unsigned int u = __float_as_uint(f);
    unsigned int r = (u + 0x7fffu + ((u >> 16) & 1u)) >> 16;
    return (unsigned short)r;
}

static __device__ __forceinline__ float gelu_f(float x) {
    return 0.5f * x * (1.f + erff(x * 0.70710678118654752f));
}

// async global->LDS, 16B per lane; LDS dest is wave-uniform base + lane*16
static __device__ __forceinline__ void gload_lds16(const void* g, void* l) {
    __builtin_amdgcn_global_load_lds(
        (const __attribute__((address_space(1))) unsigned int*)g,
        (__attribute__((address_space(3))) unsigned int*)l, 16, 0, 0);
}

// LDS index skew for FFT buffers
static __device__ __forceinline__ int ldsmap(int i) { return i + (i >> 6); }

static __device__ __forceinline__ int rev4(int k) {
    int d0 = k % 10; k /= 10;
    int d1 = k % 10; k /= 10;
    int d2 = k % 10; int d3 = k / 10;
    return d0 * 1000 + d1 * 100 + d2 * 10 + d3;
}

// forward 5-point DFT (W5 = e^{-2pi i/5}), Winograd-style
static __device__ __forceinline__ void dft5(
    float a0r, float a0i, float a1r, float a1i, float a2r, float a2i,
    float a3r, float a3i, float a4r, float a4i,
    float* Xr, float* Xi)
{
    const float c1 = 0.30901699437494742f, c2 = -0.80901699437494745f;
    const float s1 = 0.95105651629515357f, s2 = 0.58778525229247312f;
    float t1r = a1r + a4r, t1i = a1i + a4i;
    float d1r = a1r - a4r, d1i = a1i - a4i;
    float t2r = a2r + a3r, t2i = a2i + a3i;
    float d2r = a2r - a3r, d2i = a2i - a3i;
    Xr[0] = a0r + t1r + t2r; Xi[0] = a0i + t1i + t2i;
    float m1r = a0r + c1 * t1r + c2 * t2r, m1i = a0i + c1 * t1i + c2 * t2i;
    float m2r = a0r + c2 * t1r + c1 * t2r, m2i = a0i + c2 * t1i + c1 * t2i;
    float n1r = s1 * d1r + s2 * d2r, n1i = s1 * d1i + s2 * d2i;
    float n2r = s2 * d1r - s1 * d2r, n2i = s2 * d1i - s1 * d2i;
    Xr[1] = m1r + n1i; Xi[1] = m1i - n1r;
    Xr[4] = m1r - n1i; Xi[4] = m1i + n1r;
    Xr[2] = m2r + n2i; Xi[2] = m2i - n2r;
    Xr[3] = m2r - n2i; Xi[3] = m2i + n2r;
}

// ---------------------------------------------------------------------------
// FFT kernel: one block per batch row. Pack even/odd into complex len-10000,
// 4x radix-10 DIF stages (2x dft5 + register twiddle chain, NO table loads),
// mean-subtract fused into stage 0, real-FFT untangle with inline sincos.
// ---------------------------------------------------------------------------
__global__ __launch_bounds__(512, 4)
void fft_kernel(const float* __restrict__ x,
                unsigned short* __restrict__ hb,
                unsigned short* __restrict__ cb)
{
    __shared__ float reb[10156];
    __shared__ float imb[10156];
    __shared__ float redbuf[8];

    const int b = blockIdx.x;
    const int tid = threadIdx.x;
    const int lane = tid & 63;
    const int wv = tid >> 6;
    const float* xr = x + (size_t)b * 20000;

    // vectorized load + pack + row-sum (5000 float4s)
    float sum = 0.f;
    for (int i4 = tid; i4 < 5000; i4 += 512) {
        float4 v = ((const float4*)xr)[i4];
        sum += v.x + v.y + v.z + v.w;
        int n = i4 * 2;
        reb[ldsmap(n)]     = v.x; imb[ldsmap(n)]     = v.y;
        reb[ldsmap(n + 1)] = v.z; imb[ldsmap(n + 1)] = v.w;
    }
    #pragma unroll
    for (int o = 32; o; o >>= 1) sum += __shfl_xor(sum, o);
    __syncthreads();                 // pack complete + redbuf guard
    if (lane == 0) redbuf[wv] = sum;
    __syncthreads();
    float tot = 0.f;
    #pragma unroll
    for (int i = 0; i < 8; ++i) tot += redbuf[i];
    const float mean = tot * (1.f / 20000.f);

    const float WR[5] = {1.f, 0.80901699437494745f, 0.30901699437494742f,
                         -0.30901699437494742f, -0.80901699437494745f};
    const float WI[5] = {0.f, -0.58778525229247312f, -0.95105651629515357f,
                         -0.95105651629515357f, -0.58778525229247312f};

    // 4 radix-10 DIF stages; stage 0 subtracts the mean on the fly
    #pragma unroll
    for (int s = 0; s < 4; ++s) {
        const int L  = (s == 0) ? 1000 : (s == 1) ? 100 : (s == 2) ? 10 : 1;
        const int sc = (s == 0) ? 1 : (s == 1) ? 10 : (s == 2) ? 100 : 1000;
        const float mm = (s == 0) ? mean : 0.f;
        for (int w = tid; w < 1000; w += 512) {
            const int g = w / L;
            const int j = w - g * L;
            const int base = g * (10 * L) + j;
            float ar[10], ai[10];
            #pragma unroll
            for (int u = 0; u < 10; ++u) {
                int idx = ldsmap(base + u * L);
                ar[u] = reb[idx] - mm;
                ai[u] = imb[idx] - mm;
            }
            float Er[5], Ei[5], Or[5], Oi[5];
            dft5(ar[0], ai[0], ar[2], ai[2], ar[4], ai[4], ar[6], ai[6], ar[8], ai[8], Er, Ei);
            dft5(ar[1], ai[1], ar[3], ai[3], ar[5], ai[5], ar[7], ai[7], ar[9], ai[9], Or, Oi);
            #pragma unroll
            for (int k = 1; k < 5; ++k) {
                float tr = Or[k] * WR[k] - Oi[k] * WI[k];
                Oi[k] = Or[k] * WI[k] + Oi[k] * WR[k];
                Or[k] = tr;
            }
            // register twiddle powers: w1 = e^{-2pi i (j*sc)/10000}; tw[t] = w1^t
            const float ang = (float)(j * sc) * -6.28318530717958648e-4f;
            float w1c, w1s;
            __sincosf(ang, &w1s, &w1c);
            float twr[10], twi[10];
            twr[0] = 1.f; twi[0] = 0.f;
            #pragma unroll
            for (int t = 1; t < 10; ++t) {
                twr[t] = twr[t - 1] * w1c - twi[t - 1] * w1s;
                twi[t] = twr[t - 1] * w1s + twi[t - 1] * w1c;
            }
            #pragma unroll
            for (int k = 0; k < 5; ++k) {
                float xr0 = Er[k] + Or[k], xi0 = Ei[k] + Oi[k];
                float xr1 = Er[k] - Or[k], xi1 = Ei[k] - Oi[k];
                int i0 = ldsmap(base + k * L);
                int i1 = ldsmap(base + (k + 5) * L);
                if (k == 0) {
                    reb[i0] = xr0;
                    imb[i0] = xi0;
                } else {
                    reb[i0] = xr0 * twr[k] - xi0 * twi[k];
                    imb[i0] = xr0 * twi[k] + xi0 * twr[k];
                }
                reb[i1] = xr1 * twr[k + 5] - xi1 * twi[k + 5];
                imb[i1] = xr1 * twi[k + 5] + xi1 * twr[k + 5];
            }
        }
        __syncthreads();
    }

    // real-FFT untangle + log1p|X| (inline sincos twiddle, lanes consecutive)
    float harr[20];
    float sumsq = 0.f;
    unsigned short* hrow = hb + (size_t)b * 10240;
    #pragma unroll
    for (int i = 0; i < 20; ++i) {
        int k = tid + i * 512;
        float hval = 0.f;
        if (k <= 10000) {
            int k1 = (k == 10000) ? 0 : k;
            int k2 = (10000 - k) % 10000;
            int i1 = ldsmap(rev4(k1));
            int i2 = ldsmap(rev4(k2));
            float zr = reb[i1], zi = imb[i1];
            float wr = reb[i2], wi = imb[i2];
            float er = 0.5f * (zr + wr);
            float ei = 0.5f * (zi - wi);
            float odr = 0.5f * (zi + wi);
            float odi = -0.5f * (zr - wr);
            float ct, st;
            __sincosf((float)k * -3.14159265358979324e-4f, &st, &ct);
            float xre = er + ct * odr - st * odi;
            float xim = ei + ct * odi + st * odr;
            hval = log1pf(sqrtf(xre * xre + xim * xim));
        }
        harr[i] = hval;
        hrow[k] = f2bf(hval);
        sumsq += hval * hval;
    }
    #pragma unroll
    for (int o = 32; o; o >>= 1) sumsq += __shfl_xor(sumsq, o);
    __syncthreads();
    if (lane == 0) redbuf[wv] = sumsq;
    __syncthreads();
    float tsq = 0.f;
    #pragma unroll
    for (int i = 0; i < 8; ++i) tsq += redbuf[i];
    const float inv = 1.f / (sqrtf(tsq) + 1e-8f);

    unsigned short* crow = cb + (size_t)b * 10240;
    #pragma unroll
    for (int i = 0; i < 20; ++i) {
        int k = tid + i * 512;
        crow[k] = f2bf(harr[i] * harr[i] * inv);
    }
}

// ---------------------------------------------------------------------------
// Fused prep: pack W0/sigmoid(alpha0) -> bf16 padded, zero K-pads,
// transpose small weights (+sigmoid on alphas). One kernel, grid 5560x256.
// ---------------------------------------------------------------------------
__global__ __launch_bounds__(256)
void prep_kernel(const float* __restrict__ W0, const float* __restrict__ A0,
                 unsigned short* __restrict__ Wb, unsigned short* __restrict__ Sb,
                 const float* __restrict__ W1, const float* __restrict__ A1,
                 const float* __restrict__ W2, const float* __restrict__ A2,
                 float* __restrict__ W1T, float* __restrict__ S1T,
                 float* __restrict__ W2T, float* __restrict__ S2T)
{
    int idx = blockIdx.x * 256 + threadIdx.x;
    if (idx < 1280128) {
        const bool isW = idx < 640064;
        const int f4 = isW ? idx : idx - 640064;
        const float* src = isW ? W0 : A0;
        unsigned short* dst = isW ? Wb : Sb;
        float4 v = ((const float4*)src)[f4];
        float e[4] = {v.x, v.y, v.z, v.w};
        int flat = f4 * 4;
        int row = flat / 10001;
        int col = flat - row * 10001;
        #pragma unroll
        for (int i = 0; i < 4; ++i) {
            if (col == 10001) { row++; col = 0; }
            float val = isW ? e[i] : 1.f / (1.f + expf(-e[i]));
            dst[(size_t)row * 10240 + col] = f2bf(val);
            col++;
        }
    } else if (idx < 1341312) {
        int i = idx - 1280128;              // 256*239 pads
        int row = i / 239;
        int col = 10001 + (i - row * 239);
        Wb[(size_t)row * 10240 + col] = 0;
        Sb[(size_t)row * 10240 + col] = 0;
    } else if (idx < 1423232) {
        int o = idx - 1341312;              // 0..81919
        if (o < 32768) {
            int d = o >> 7, h = o & 127;
            W1T[o] = W1[h * 256 + d];
        } else if (o < 65536) {
            int p = o - 32768;
            int d = p >> 7, h = p & 127;
            S1T[p] = 1.f / (1.f + expf(-A1[h * 256 + d]));
        } else if (o < 73728) {
            int p = o - 65536;
            int d = p >> 6, h = p & 63;
            W2T[p] = W2[h * 128 + d];
        } else {
            int p = o - 73728;
            int d = p >> 6, h = p & 63;
            S2T[p] = 1.f / (1.f + expf(-A2[h * 128 + d]));
        }
    }
}

// ---------------------------------------------------------------------------
// Layer-0 dual GEMM, m97-style: BM=128 BN=64 BK=64, split-K=16 (10 steps),
// global_load_lds 16B staging with XOR k-chunk swizzle. grid (8,4,16) x 256.
// ---------------------------------------------------------------------------
__global__ __launch_bounds__(256, 2)
void gemm0_kernel(const unsigned short* __restrict__ hb, const unsigned short* __restrict__ cb,
                  const unsigned short* __restrict__ Wb, const unsigned short* __restrict__ Sb,
                  float* __restrict__ Py, float* __restrict__ Pp)
{
    __shared__ unsigned short Ah[128 * 64];
    __shared__ unsigned short Ac[128 * 64];
    __shared__ unsigned short Bw[64 * 64];
    __shared__ unsigned short Bs[64 * 64];

    const int t = threadIdx.x;
    const int b0 = blockIdx.x * 128;
    const int n0 = blockIdx.y * 64;
    const int z = blockIdx.z;
    const int lane = t & 63;
    const int wv = t >> 6;
    const int ml = lane & 15;
    const int q4 = lane >> 4;
    const int s0 = q4 ^ (ml & 7);

    const int sub = lane >> 3;
    const int sl = lane & 7;
    const int gsw = sl ^ sub;

    f32x4 accY[2][4], accP[2][4];
    #pragma unroll
    for (int mt = 0; mt < 2; ++mt)
        #pragma unroll
        for (int nt = 0; nt < 4; ++nt) {
            accY[mt][nt] = (f32x4){0.f, 0.f, 0.f, 0.f};
            accP[mt][nt] = (f32x4){0.f, 0.f, 0.f, 0.f};
        }

    const int kbase = z * 640;

    for (int step = 0; step < 10; ++step) {
        const int k0 = kbase + step * 64;
        __syncthreads();
        #pragma unroll
        for (int j = 0; j < 4; ++j) {
            const int c = wv * 4 + j;
            const size_t go = (size_t)(b0 + c * 8 + sub) * 10240 + k0 + gsw * 8;
            gload_lds16(&hb[go], &Ah[c * 512]);
            gload_lds16(&cb[go], &Ac[c * 512]);
        }
        #pragma unroll
        for (int j = 0; j < 2; ++j) {
            const int c = wv * 2 + j;
            const size_t go = (size_t)(n0 + c * 8 + sub) * 10240 + k0 + gsw * 8;
            gload_lds16(&Wb[go], &Bw[c * 512]);
            gload_lds16(&Sb[go], &Bs[c * 512]);
        }
        __syncthreads();

        #pragma unroll
        for (int kk = 0; kk < 2; ++kk) {
            const int slot = (s0 ^ (kk << 2)) << 3;
            bf16x8 ah[2], ac[2], bw[4], bs[4];
            #pragma unroll
            for (int mt = 0; mt < 2; ++mt) {
                int mrow = wv * 32 + mt * 16 + ml;
                ah[mt] = *(const bf16x8*)&Ah[mrow * 64 + slot];
                ac[mt] = *(const bf16x8*)&Ac[mrow * 64 + slot];
            }
            #pragma unroll
            for (int nt = 0; nt < 4; ++nt) {
                int nrow = nt * 16 + ml;
                bw[nt] = *(const bf16x8*)&Bw[nrow * 64 + slot];
                bs[nt] = *(const bf16x8*)&Bs[nrow * 64 + slot];
            }
            #pragma unroll
            for (int mt = 0; mt < 2; ++mt)
                #pragma unroll
                for (int nt = 0; nt < 4; ++nt) {
                    accY[mt][nt] = __builtin_amdgcn_mfma_f32_16x16x32_bf16(ah[mt], bw[nt], accY[mt][nt], 0, 0, 0);
                    accP[mt][nt] = __builtin_amdgcn_mfma_f32_16x16x32_bf16(ac[mt], bs[nt], accP[mt][nt], 0, 0, 0);
                }
        }
    }

    const int rq = q4 * 4;
    #pragma unroll
    for (int mt = 0; mt < 2; ++mt)
        #pragma unroll
        for (int nt = 0; nt < 4; ++nt)
            #pragma unroll
            for (int r = 0; r < 4; ++r) {
                int m = b0 + wv * 32 + mt * 16 + rq + r;
                int n = n0 + nt * 16 + ml;
                size_t o = ((size_t)z * 1024 + m) * 256 + n;
                Py[o] = accY[mt][nt][r];
                Pp[o] = accP[mt][nt][r];
            }
}

// ---------------------------------------------------------------------------
// Combine splits + bias + plastic + LayerNorm(256) + GELU + c for next layer.
// ---------------------------------------------------------------------------
__global__ __launch_bounds__(256)
void combine0_kernel(const float* __restrict__ Py, const float* __restrict__ Pp,
                     const float* __restrict__ b0v, const float* __restrict__ eta0p,
                     const float* __restrict__ g0, const float* __restrict__ be0,
                     float* __restrict__ h1, float* __restrict__ c1)
{
    __shared__ float red[4];
    const int b = blockIdx.x;
    const int h = threadIdx.x;
    const int lane = h & 63;
    const int wv = h >> 6;

    float ys = 0.f, ps = 0.f;
    for (int s = 0; s < 16; ++s) {
        size_t o = ((size_t)s * 1024 + b) * 256 + h;
        ys += Py[o];
        ps += Pp[o];
    }
    float y = ys + b0v[h];
    float v = y + eta0p[0] * tanhf(y) * ps;

    float s1 = v;
    #pragma unroll
    for (int o = 32; o; o >>= 1) s1 += __shfl_xor(s1, o);
    __syncthreads();
    if (lane == 0) red[wv] = s1;
    __syncthreads();
    float sum = red[0] + red[1] + red[2] + red[3];

    float s2 = v * v;
    #pragma unroll
    for (int o = 32; o; o >>= 1) s2 += __shfl_xor(s2, o);
    __syncthreads();
    if (lane == 0) red[wv] = s2;
    __syncthreads();
    float sumsq = red[0] + red[1] + red[2] + red[3];

    float mu = sum * (1.f / 256.f);
    float var = sumsq * (1.f / 256.f) - mu * mu;
    float u = (v - mu) * rsqrtf(var + 1e-5f) * g0[h] + be0[h];
    float gl = gelu_f(u);

    float s3 = gl * gl;
    #pragma unroll
    for (int o = 32; o; o >>= 1) s3 += __shfl_xor(s3, o);
    __syncthreads();
    if (lane == 0) red[wv] = s3;
    __syncthreads();
    float gsq = red[0] + red[1] + red[2] + red[3];
    float inv = 1.f / (sqrtf(gsq) + 1e-8f);

    h1[(size_t)b * 256 + h] = gl;
    c1[(size_t)b * 256 + h] = gl * gl * inv;
}

// ---------------------------------------------------------------------------
// Tail: layers 1,2 + head, fp32. 8 rows per block. grid 128, block 256.
// ---------------------------------------------------------------------------
__global__ __launch_bounds__(256)
void tail_kernel(const float* __restrict__ h1, const float* __restrict__ c1,
                 const float* __restrict__ W1T, const float* __restrict__ S1T,
                 const float* __restrict__ b1, const float* __restrict__ eta1p,
                 const float* __restrict__ g1, const float* __restrict__ be1,
                 const float* __restrict__ W2T, const float* __restrict__ S2T,
                 const float* __restrict__ b2, const float* __restrict__ eta2p,
                 const float* __restrict__ g2, const float* __restrict__ be2,
                 const float* __restrict__ hw, const float* __restrict__ hbod,
                 float* __restrict__ out)
{
    __shared__ float sh[8][256];
    __shared__ float sc[8][256];
    __shared__ float sv[8][128];
    __shared__ float sh2[8][128];
    __shared__ float sc2[8][128];
    __shared__ float sv2[8][64];

    const int t = threadIdx.x;
    const int b0 = blockIdx.x * 8;
    const int lane = t & 63;
    const int wv = t >> 6;

    #pragma unroll
    for (int i = 0; i < 8; ++i) {
        int idx = t + i * 256;
        int r = idx >> 8, d = idx & 255;
        sh[r][d] = h1[(size_t)(b0 + r) * 256 + d];
        sc[r][d] = c1[(size_t)(b0 + r) * 256 + d];
    }
    __syncthreads();

    const int hcol = t & 127;
    const int r2 = t >> 7;
    float ya[4] = {0.f, 0.f, 0.f, 0.f};
    float pa[4] = {0.f, 0.f, 0.f, 0.f};
    for (int d = 0; d < 256; ++d) {
        float w = W1T[d * 128 + hcol];
        float s = S1T[d * 128 + hcol];
        #pragma unroll
        for (int i = 0; i < 4; ++i) {
            int r = r2 * 4 + i;
            ya[i] += sh[r][d] * w;
            pa[i] += sc[r][d] * s;
        }
    }
    const float e1 = eta1p[0];
    #pragma unroll
    for (int i = 0; i < 4; ++i) {
        int r = r2 * 4 + i;
        float y = ya[i] + b1[hcol];
        sv[r][hcol] = y + e1 * tanhf(y) * pa[i];
    }
    __syncthreads();

    #pragma unroll
    for (int rr = 0; rr < 2; ++rr) {
        int r = wv * 2 + rr;
        float v0 = sv[r][lane];
        float v1 = sv[r][lane + 64];
        float s = v0 + v1, sq = v0 * v0 + v1 * v1;
        #pragma unroll
        for (int o = 32; o; o >>= 1) { s += __shfl_xor(s, o); sq += __shfl_xor(sq, o); }
        float mu = s * (1.f / 128.f);
        float var = sq * (1.f / 128.f) - mu * mu;
        float rs = rsqrtf(var + 1e-5f);
        float u0 = (v0 - mu) * rs * g1[lane] + be1[lane];
        float u1 = (v1 - mu) * rs * g1[lane + 64] + be1[lane + 64];
        float ge0 = gelu_f(u0);
        float ge1 = gelu_f(u1);
        float gsq = ge0 * ge0 + ge1 * ge1;
        #pragma unroll
        for (int o = 32; o; o >>= 1) gsq += __shfl_xor(gsq, o);
        float inv = 1.f / (sqrtf(gsq) + 1e-8f);
        sh2[r][lane] = ge0; sh2[r][lane + 64] = ge1;
        sc2[r][lane] = ge0 * ge0 * inv; sc2[r][lane + 64] = ge1 * ge1 * inv;
    }
    __syncthreads();

    const int h2c = t & 63;
    const int r4 = t >> 6;
    float yb[2] = {0.f, 0.f};
    float pb[2] = {0.f, 0.f};
    for (int d = 0; d < 128; ++d) {
        float w = W2T[d * 64 + h2c];
        float s = S2T[d * 64 + h2c];
        #pragma unroll
        for (int i = 0; i < 2; ++i) {
            int r = r4 * 2 + i;
            yb[i] += sh2[r][d] * w;
            pb[i] += sc2[r][d] * s;
        }
    }
    const float e2 = eta2p[0];
    #pragma unroll
    for (int i = 0; i < 2; ++i) {
        int r = r4 * 2 + i;
        float y = yb[i] + b2[h2c];
        sv2[r][h2c] = y + e2 * tanhf(y) * pb[i];
    }
    __syncthreads();

    #pragma unroll
    for (int rr = 0; rr < 2; ++rr) {
        int r = wv * 2 + rr;
        float v0 = sv2[r][lane];
        float s = v0, sq = v0 * v0;
        #pragma unroll
        for (int o = 32; o; o >>= 1) { s += __shfl_xor(s, o); sq += __shfl_xor(sq, o); }
        float mu = s * (1.f / 64.f);
        float var = sq * (1.f / 64.f) - mu * mu;
        float rs = rsqrtf(var + 1e-5f);
        float u = (v0 - mu) * rs * g2[lane] + be2[lane];
        float g = gelu_f(u);
        float hc = g * hw[lane];
        #pragma unroll
        for (int o = 32; o; o >>= 1) hc += __shfl_xor(hc, o);
        if (lane == 0) out[b0 + r] = hc + hbod[0];
    }
}

// ---------------------------------------------------------------------------
extern "C" void kernel_launch(void* const* d_in, const int* in_sizes, int n_in,
                              void* d_out, int out_size, void* d_ws, size_t ws_size,
                              hipStream_t stream)
{
    const float* x    = (const float*)d_in[0];
    const float* W0   = (const float*)d_in[1];
    const float* A0   = (const float*)d_in[2];
    const float* b0   = (const float*)d_in[3];
    const float* eta0 = (const float*)d_in[4];
    const float* g0   = (const float*)d_in[5];
    const float* be0  = (const float*)d_in[6];
    const float* W1   = (const float*)d_in[7];
    const float* A1   = (const float*)d_in[8];
    const float* b1   = (const float*)d_in[9];
    const float* eta1 = (const float*)d_in[10];
    const float* g1   = (const float*)d_in[11];
    const float* be1  = (const float*)d_in[12];
    const float* W2   = (const float*)d_in[13];
    const float* A2   = (const float*)d_in[14];
    const float* b2   = (const float*)d_in[15];
    const float* eta2 = (const float*)d_in[16];
    const float* g2   = (const float*)d_in[17];
    const float* be2  = (const float*)d_in[18];
    const float* hw   = (const float*)d_in[19];
    const float* hbod = (const float*)d_in[20];
    float* out = (float*)d_out;

    char* w = (char*)d_ws;
    unsigned short* hb  = (unsigned short*)(w + 0);          // 20971520
    unsigned short* cb  = (unsigned short*)(w + 20971520);   // 20971520
    unsigned short* Wb0 = (unsigned short*)(w + 41943040);   // 5242880
    unsigned short* Sb0 = (unsigned short*)(w + 47185920);   // 5242880
    float* Py  = (float*)(w + 52428800);                     // 16777216
    float* Pp  = (float*)(w + 69206016);                     // 16777216
    float* h1  = (float*)(w + 85983232);                     // 1048576
    float* c1  = (float*)(w + 87031808);                     // 1048576
    float* W1T = (float*)(w + 88080384);                     // 131072
    float* S1T = (float*)(w + 88211456);                     // 131072
    float* W2T = (float*)(w + 88342528);                     // 32768
    float* S2T = (float*)(w + 88375296);                     // 32768

    hipLaunchKernelGGL(fft_kernel, dim3(1024), dim3(512), 0, stream, x, hb, cb);
    hipLaunchKernelGGL(prep_kernel, dim3(5560), dim3(256), 0, stream,
                       W0, A0, Wb0, Sb0, W1, A1, W2, A2, W1T, S1T, W2T, S2T);
    hipLaunchKernelGGL(gemm0_kernel, dim3(8, 4, 16), dim3(256), 0, stream, hb, cb, Wb0, Sb0, Py, Pp);
    hipLaunchKernelGGL(combine0_kernel, dim3(1024), dim3(256), 0, stream, Py, Pp, b0, eta0, g0, be0, h1, c1);
    hipLaunchKernelGGL(tail_kernel, dim3(128), dim3(256), 0, stream, h1, c1, W1T, S1T, b1, eta1, g1, be1,
                       W2T, S2T, b2, eta2, g2, be2, hw, hbod, out);
}

// Round 5
// 281.915 us; speedup vs baseline: 1.5142x; 1.0489x over previous
//
#include <hip/hip_runtime.h>
#include <hip/hip_bf16.h>
#include <math.h>

typedef short bf16x8 __attribute__((ext_vector_type(8)));
typedef float f32x4 __attribute__((ext_vector_type(4)));

static __device__ __forceinline__ unsigned short f2bf(float f) {
    unsigned int u = __float_as_uint(f);
    unsigned int r = (u + 0x7fffu + ((u >> 16) & 1u)) >> 16;
    return (unsigned short)r;
}

static __device__ __forceinline__ float gelu_f(float x) {
    return 0.5f * x * (1.f + erff(x * 0.70710678118654752f));
}

// async global->LDS, 16B per lane; LDS dest is wave-uniform base + lane*16
static __device__ __forceinline__ void gload_lds16(const void* g, void* l) {
    __builtin_amdgcn_global_load_lds(
        (const __attribute__((address_space(1))) unsigned int*)g,
        (__attribute__((address_space(3))) unsigned int*)l, 16, 0, 0);
}

// LDS index skew for FFT buffers
static __device__ __forceinline__ int ldsmap(int i) { return i + (i >> 6); }

static __device__ __forceinline__ int rev4(int k) {
    int d0 = k % 10; k /= 10;
    int d1 = k % 10; k /= 10;
    int d2 = k % 10; int d3 = k / 10;
    return d0 * 1000 + d1 * 100 + d2 * 10 + d3;
}

// forward 5-point DFT (W5 = e^{-2pi i/5}), Winograd-style
static __device__ __forceinline__ void dft5(
    float a0r, float a0i, float a1r, float a1i, float a2r, float a2i,
    float a3r, float a3i, float a4r, float a4i,
    float* Xr, float* Xi)
{
    const float c1 = 0.30901699437494742f, c2 = -0.80901699437494745f;
    const float s1 = 0.95105651629515357f, s2 = 0.58778525229247312f;
    float t1r = a1r + a4r, t1i = a1i + a4i;
    float d1r = a1r - a4r, d1i = a1i - a4i;
    float t2r = a2r + a3r, t2i = a2i + a3i;
    float d2r = a2r - a3r, d2i = a2i - a3i;
    Xr[0] = a0r + t1r + t2r; Xi[0] = a0i + t1i + t2i;
    float m1r = a0r + c1 * t1r + c2 * t2r, m1i = a0i + c1 * t1i + c2 * t2i;
    float m2r = a0r + c2 * t1r + c1 * t2r, m2i = a0i + c2 * t1i + c1 * t2i;
    float n1r = s1 * d1r + s2 * d2r, n1i = s1 * d1i + s2 * d2i;
    float n2r = s2 * d1r - s1 * d2r, n2i = s2 * d1i - s1 * d2i;
    Xr[1] = m1r + n1i; Xi[1] = m1i - n1r;
    Xr[4] = m1r - n1i; Xi[4] = m1i + n1r;
    Xr[2] = m2r + n2i; Xi[2] = m2i - n2r;
    Xr[3] = m2r - n2i; Xi[3] = m2i + n2r;
}

// One radix-10 DIF stage, specialized per stage index:
// S=0: g=0, j=w, fused mean-subtract. S=3: g=w, j=0, twiddles == 1 (skipped).
template<int S>
static __device__ __forceinline__ void radix10_stage(
    float* __restrict__ reb, float* __restrict__ imb, int tid, float mean)
{
    constexpr int L  = (S == 0) ? 1000 : (S == 1) ? 100 : (S == 2) ? 10 : 1;
    constexpr int SC = (S == 0) ? 1 : (S == 1) ? 10 : (S == 2) ? 100 : 1000;
    constexpr bool TW = (S != 3);

    const float WR[5] = {1.f, 0.80901699437494745f, 0.30901699437494742f,
                         -0.30901699437494742f, -0.80901699437494745f};
    const float WI[5] = {0.f, -0.58778525229247312f, -0.95105651629515357f,
                         -0.95105651629515357f, -0.58778525229247312f};

    for (int w = tid; w < 1000; w += 512) {
        int g, j;
        if (S == 0)      { g = 0; j = w; }
        else if (S == 3) { g = w; j = 0; }
        else             { g = w / L; j = w - g * L; }
        const int base = g * (10 * L) + j;

        float ar[10], ai[10];
        #pragma unroll
        for (int u = 0; u < 10; ++u) {
            int idx = ldsmap(base + u * L);
            ar[u] = reb[idx];
            ai[u] = imb[idx];
        }
        if (S == 0) {
            #pragma unroll
            for (int u = 0; u < 10; ++u) { ar[u] -= mean; ai[u] -= mean; }
        }

        float Er[5], Ei[5], Or[5], Oi[5];
        dft5(ar[0], ai[0], ar[2], ai[2], ar[4], ai[4], ar[6], ai[6], ar[8], ai[8], Er, Ei);
        dft5(ar[1], ai[1], ar[3], ai[3], ar[5], ai[5], ar[7], ai[7], ar[9], ai[9], Or, Oi);
        #pragma unroll
        for (int k = 1; k < 5; ++k) {
            float tr = Or[k] * WR[k] - Oi[k] * WI[k];
            Oi[k] = Or[k] * WI[k] + Oi[k] * WR[k];
            Or[k] = tr;
        }

        if (TW) {
            const float ang = (float)(j * SC) * -6.28318530717958648e-4f;
            float w1c, w1s;
            __sincosf(ang, &w1s, &w1c);
            float twr[10], twi[10];
            twr[0] = 1.f; twi[0] = 0.f;
            #pragma unroll
            for (int t = 1; t < 10; ++t) {
                twr[t] = twr[t - 1] * w1c - twi[t - 1] * w1s;
                twi[t] = twr[t - 1] * w1s + twi[t - 1] * w1c;
            }
            #pragma unroll
            for (int k = 0; k < 5; ++k) {
                float xr0 = Er[k] + Or[k], xi0 = Ei[k] + Oi[k];
                float xr1 = Er[k] - Or[k], xi1 = Ei[k] - Oi[k];
                int i0 = ldsmap(base + k * L);
                int i1 = ldsmap(base + (k + 5) * L);
                if (k == 0) {
                    reb[i0] = xr0;
                    imb[i0] = xi0;
                } else {
                    reb[i0] = xr0 * twr[k] - xi0 * twi[k];
                    imb[i0] = xr0 * twi[k] + xi0 * twr[k];
                }
                reb[i1] = xr1 * twr[k + 5] - xi1 * twi[k + 5];
                imb[i1] = xr1 * twi[k + 5] + xi1 * twr[k + 5];
            }
        } else {
            #pragma unroll
            for (int k = 0; k < 5; ++k) {
                int i0 = ldsmap(base + k * L);
                int i1 = ldsmap(base + (k + 5) * L);
                reb[i0] = Er[k] + Or[k]; imb[i0] = Ei[k] + Oi[k];
                reb[i1] = Er[k] - Or[k]; imb[i1] = Ei[k] - Oi[k];
            }
        }
    }
}

// ---------------------------------------------------------------------------
// Fused FFT + prep. Blocks [0,1024): one FFT row each (512 thr, 81 KB LDS,
// 2 blocks/CU). Blocks [1024, 3804): weight prep (pack W0/sig(alpha0) to bf16
// padded, zero pads, transpose small weights) — memory-bound, co-schedules
// with the VALU-bound FFT blocks.
// ---------------------------------------------------------------------------
__global__ __launch_bounds__(512, 4)
void fft_prep_kernel(const float* __restrict__ x,
                     unsigned short* __restrict__ hb,
                     unsigned short* __restrict__ cb,
                     const float* __restrict__ W0, const float* __restrict__ A0,
                     unsigned short* __restrict__ Wb, unsigned short* __restrict__ Sb,
                     const float* __restrict__ W1, const float* __restrict__ A1,
                     const float* __restrict__ W2, const float* __restrict__ A2,
                     float* __restrict__ W1T, float* __restrict__ S1T,
                     float* __restrict__ W2T, float* __restrict__ S2T)
{
    if (blockIdx.x >= 1024) {
        // ---- prep path ----
        int idx = (blockIdx.x - 1024) * 512 + threadIdx.x;
        if (idx < 1280128) {
            const bool isW = idx < 640064;
            const int f4 = isW ? idx : idx - 640064;
            const float* src = isW ? W0 : A0;
            unsigned short* dst = isW ? Wb : Sb;
            float4 v = ((const float4*)src)[f4];
            float e[4] = {v.x, v.y, v.z, v.w};
            int flat = f4 * 4;
            int row = flat / 10001;
            int col = flat - row * 10001;
            #pragma unroll
            for (int i = 0; i < 4; ++i) {
                if (col == 10001) { row++; col = 0; }
                float val = isW ? e[i] : 1.f / (1.f + expf(-e[i]));
                dst[(size_t)row * 10240 + col] = f2bf(val);
                col++;
            }
        } else if (idx < 1341312) {
            int i = idx - 1280128;              // 256*239 pads
            int row = i / 239;
            int col = 10001 + (i - row * 239);
            Wb[(size_t)row * 10240 + col] = 0;
            Sb[(size_t)row * 10240 + col] = 0;
        } else if (idx < 1423232) {
            int o = idx - 1341312;              // 0..81919
            if (o < 32768) {
                int d = o >> 7, h = o & 127;
                W1T[o] = W1[h * 256 + d];
            } else if (o < 65536) {
                int p = o - 32768;
                int d = p >> 7, h = p & 127;
                S1T[p] = 1.f / (1.f + expf(-A1[h * 256 + d]));
            } else if (o < 73728) {
                int p = o - 65536;
                int d = p >> 6, h = p & 63;
                W2T[p] = W2[h * 128 + d];
            } else {
                int p = o - 73728;
                int d = p >> 6, h = p & 63;
                S2T[p] = 1.f / (1.f + expf(-A2[h * 128 + d]));
            }
        }
        return;
    }

    // ---- FFT path ----
    __shared__ float reb[10156];
    __shared__ float imb[10156];
    __shared__ float redbuf[8];

    const int b = blockIdx.x;
    const int tid = threadIdx.x;
    const int lane = tid & 63;
    const int wv = tid >> 6;
    const float* xr = x + (size_t)b * 20000;

    // vectorized load + pack + row-sum (5000 float4s)
    float sum = 0.f;
    for (int i4 = tid; i4 < 5000; i4 += 512) {
        float4 v = ((const float4*)xr)[i4];
        sum += v.x + v.y + v.z + v.w;
        int n = i4 * 2;
        reb[ldsmap(n)]     = v.x; imb[ldsmap(n)]     = v.y;
        reb[ldsmap(n + 1)] = v.z; imb[ldsmap(n + 1)] = v.w;
    }
    #pragma unroll
    for (int o = 32; o; o >>= 1) sum += __shfl_xor(sum, o);
    __syncthreads();                 // pack complete + redbuf guard
    if (lane == 0) redbuf[wv] = sum;
    __syncthreads();
    float tot = 0.f;
    #pragma unroll
    for (int i = 0; i < 8; ++i) tot += redbuf[i];
    const float mean = tot * (1.f / 20000.f);

    radix10_stage<0>(reb, imb, tid, mean);
    __syncthreads();
    radix10_stage<1>(reb, imb, tid, 0.f);
    __syncthreads();
    radix10_stage<2>(reb, imb, tid, 0.f);
    __syncthreads();
    radix10_stage<3>(reb, imb, tid, 0.f);
    __syncthreads();

    // real-FFT untangle + log1p|X| (inline sincos twiddle, lanes consecutive)
    float harr[20];
    float sumsq = 0.f;
    unsigned short* hrow = hb + (size_t)b * 10240;
    #pragma unroll
    for (int i = 0; i < 20; ++i) {
        int k = tid + i * 512;
        float hval = 0.f;
        if (k <= 10000) {
            int k1 = (k == 10000) ? 0 : k;
            int k2 = (10000 - k) % 10000;
            int i1 = ldsmap(rev4(k1));
            int i2 = ldsmap(rev4(k2));
            float zr = reb[i1], zi = imb[i1];
            float wr = reb[i2], wi = imb[i2];
            float er = 0.5f * (zr + wr);
            float ei = 0.5f * (zi - wi);
            float odr = 0.5f * (zi + wi);
            float odi = -0.5f * (zr - wr);
            float ct, st;
            __sincosf((float)k * -3.14159265358979324e-4f, &st, &ct);
            float xre = er + ct * odr - st * odi;
            float xim = ei + ct * odi + st * odr;
            hval = log1pf(sqrtf(xre * xre + xim * xim));
        }
        harr[i] = hval;
        hrow[k] = f2bf(hval);
        sumsq += hval * hval;
    }
    #pragma unroll
    for (int o = 32; o; o >>= 1) sumsq += __shfl_xor(sumsq, o);
    __syncthreads();
    if (lane == 0) redbuf[wv] = sumsq;
    __syncthreads();
    float tsq = 0.f;
    #pragma unroll
    for (int i = 0; i < 8; ++i) tsq += redbuf[i];
    const float inv = 1.f / (sqrtf(tsq) + 1e-8f);

    unsigned short* crow = cb + (size_t)b * 10240;
    #pragma unroll
    for (int i = 0; i < 20; ++i) {
        int k = tid + i * 512;
        crow[k] = f2bf(harr[i] * harr[i] * inv);
    }
}

// ---------------------------------------------------------------------------
// Layer-0 dual GEMM, m97-style: BM=128 BN=64 BK=64, split-K=16 (10 steps),
// global_load_lds 16B staging with XOR k-chunk swizzle. grid (8,4,16) x 256.
// ---------------------------------------------------------------------------
__global__ __launch_bounds__(256, 2)
void gemm0_kernel(const unsigned short* __restrict__ hb, const unsigned short* __restrict__ cb,
                  const unsigned short* __restrict__ Wb, const unsigned short* __restrict__ Sb,
                  float* __restrict__ Py, float* __restrict__ Pp)
{
    __shared__ unsigned short Ah[128 * 64];
    __shared__ unsigned short Ac[128 * 64];
    __shared__ unsigned short Bw[64 * 64];
    __shared__ unsigned short Bs[64 * 64];

    const int t = threadIdx.x;
    const int b0 = blockIdx.x * 128;
    const int n0 = blockIdx.y * 64;
    const int z = blockIdx.z;
    const int lane = t & 63;
    const int wv = t >> 6;
    const int ml = lane & 15;
    const int q4 = lane >> 4;
    const int s0 = q4 ^ (ml & 7);

    const int sub = lane >> 3;
    const int sl = lane & 7;
    const int gsw = sl ^ sub;

    f32x4 accY[2][4], accP[2][4];
    #pragma unroll
    for (int mt = 0; mt < 2; ++mt)
        #pragma unroll
        for (int nt = 0; nt < 4; ++nt) {
            accY[mt][nt] = (f32x4){0.f, 0.f, 0.f, 0.f};
            accP[mt][nt] = (f32x4){0.f, 0.f, 0.f, 0.f};
        }

    const int kbase = z * 640;

    for (int step = 0; step < 10; ++step) {
        const int k0 = kbase + step * 64;
        __syncthreads();
        #pragma unroll
        for (int j = 0; j < 4; ++j) {
            const int c = wv * 4 + j;
            const size_t go = (size_t)(b0 + c * 8 + sub) * 10240 + k0 + gsw * 8;
            gload_lds16(&hb[go], &Ah[c * 512]);
            gload_lds16(&cb[go], &Ac[c * 512]);
        }
        #pragma unroll
        for (int j = 0; j < 2; ++j) {
            const int c = wv * 2 + j;
            const size_t go = (size_t)(n0 + c * 8 + sub) * 10240 + k0 + gsw * 8;
            gload_lds16(&Wb[go], &Bw[c * 512]);
            gload_lds16(&Sb[go], &Bs[c * 512]);
        }
        __syncthreads();

        #pragma unroll
        for (int kk = 0; kk < 2; ++kk) {
            const int slot = (s0 ^ (kk << 2)) << 3;
            bf16x8 ah[2], ac[2], bw[4], bs[4];
            #pragma unroll
            for (int mt = 0; mt < 2; ++mt) {
                int mrow = wv * 32 + mt * 16 + ml;
                ah[mt] = *(const bf16x8*)&Ah[mrow * 64 + slot];
                ac[mt] = *(const bf16x8*)&Ac[mrow * 64 + slot];
            }
            #pragma unroll
            for (int nt = 0; nt < 4; ++nt) {
                int nrow = nt * 16 + ml;
                bw[nt] = *(const bf16x8*)&Bw[nrow * 64 + slot];
                bs[nt] = *(const bf16x8*)&Bs[nrow * 64 + slot];
            }
            #pragma unroll
            for (int mt = 0; mt < 2; ++mt)
                #pragma unroll
                for (int nt = 0; nt < 4; ++nt) {
                    accY[mt][nt] = __builtin_amdgcn_mfma_f32_16x16x32_bf16(ah[mt], bw[nt], accY[mt][nt], 0, 0, 0);
                    accP[mt][nt] = __builtin_amdgcn_mfma_f32_16x16x32_bf16(ac[mt], bs[nt], accP[mt][nt], 0, 0, 0);
                }
        }
    }

    const int rq = q4 * 4;
    #pragma unroll
    for (int mt = 0; mt < 2; ++mt)
        #pragma unroll
        for (int nt = 0; nt < 4; ++nt)
            #pragma unroll
            for (int r = 0; r < 4; ++r) {
                int m = b0 + wv * 32 + mt * 16 + rq + r;
                int n = n0 + nt * 16 + ml;
                size_t o = ((size_t)z * 1024 + m) * 256 + n;
                Py[o] = accY[mt][nt][r];
                Pp[o] = accP[mt][nt][r];
            }
}

// ---------------------------------------------------------------------------
// Combine splits + bias + plastic + LayerNorm(256) + GELU + c for next layer.
// ---------------------------------------------------------------------------
__global__ __launch_bounds__(256)
void combine0_kernel(const float* __restrict__ Py, const float* __restrict__ Pp,
                     const float* __restrict__ b0v, const float* __restrict__ eta0p,
                     const float* __restrict__ g0, const float* __restrict__ be0,
                     float* __restrict__ h1, float* __restrict__ c1)
{
    __shared__ float red[4];
    const int b = blockIdx.x;
    const int h = threadIdx.x;
    const int lane = h & 63;
    const int wv = h >> 6;

    float ys = 0.f, ps = 0.f;
    for (int s = 0; s < 16; ++s) {
        size_t o = ((size_t)s * 1024 + b) * 256 + h;
        ys += Py[o];
        ps += Pp[o];
    }
    float y = ys + b0v[h];
    float v = y + eta0p[0] * tanhf(y) * ps;

    float s1 = v;
    #pragma unroll
    for (int o = 32; o; o >>= 1) s1 += __shfl_xor(s1, o);
    __syncthreads();
    if (lane == 0) red[wv] = s1;
    __syncthreads();
    float sum = red[0] + red[1] + red[2] + red[3];

    float s2 = v * v;
    #pragma unroll
    for (int o = 32; o; o >>= 1) s2 += __shfl_xor(s2, o);
    __syncthreads();
    if (lane == 0) red[wv] = s2;
    __syncthreads();
    float sumsq = red[0] + red[1] + red[2] + red[3];

    float mu = sum * (1.f / 256.f);
    float var = sumsq * (1.f / 256.f) - mu * mu;
    float u = (v - mu) * rsqrtf(var + 1e-5f) * g0[h] + be0[h];
    float gl = gelu_f(u);

    float s3 = gl * gl;
    #pragma unroll
    for (int o = 32; o; o >>= 1) s3 += __shfl_xor(s3, o);
    __syncthreads();
    if (lane == 0) red[wv] = s3;
    __syncthreads();
    float gsq = red[0] + red[1] + red[2] + red[3];
    float inv = 1.f / (sqrtf(gsq) + 1e-8f);

    h1[(size_t)b * 256 + h] = gl;
    c1[(size_t)b * 256 + h] = gl * gl * inv;
}

// ---------------------------------------------------------------------------
// Tail: layers 1,2 + head, fp32. 4 rows per block. grid 256, block 256.
// ---------------------------------------------------------------------------
__global__ __launch_bounds__(256)
void tail_kernel(const float* __restrict__ h1, const float* __restrict__ c1,
                 const float* __restrict__ W1T, const float* __restrict__ S1T,
                 const float* __restrict__ b1, const float* __restrict__ eta1p,
                 const float* __restrict__ g1, const float* __restrict__ be1,
                 const float* __restrict__ W2T, const float* __restrict__ S2T,
                 const float* __restrict__ b2, const float* __restrict__ eta2p,
                 const float* __restrict__ g2, const float* __restrict__ be2,
                 const float* __restrict__ hw, const float* __restrict__ hbod,
                 float* __restrict__ out)
{
    __shared__ float sh[4][256];
    __shared__ float sc[4][256];
    __shared__ float sv[4][128];
    __shared__ float sh2[4][128];
    __shared__ float sc2[4][128];
    __shared__ float sv2[4][64];

    const int t = threadIdx.x;
    const int b0 = blockIdx.x * 4;
    const int lane = t & 63;
    const int wv = t >> 6;

    #pragma unroll
    for (int i = 0; i < 4; ++i) {
        int idx = t + i * 256;
        int r = idx >> 8, d = idx & 255;
        sh[r][d] = h1[(size_t)(b0 + r) * 256 + d];
        sc[r][d] = c1[(size_t)(b0 + r) * 256 + d];
    }
    __syncthreads();

    // layer 1: 128 outputs x 4 rows; each thread 2 rows
    const int hcol = t & 127;
    const int r2 = t >> 7;           // 0..1
    float ya[2] = {0.f, 0.f};
    float pa[2] = {0.f, 0.f};
    for (int d = 0; d < 256; ++d) {
        float w = W1T[d * 128 + hcol];
        float s = S1T[d * 128 + hcol];
        #pragma unroll
        for (int i = 0; i < 2; ++i) {
            int r = r2 * 2 + i;
            ya[i] += sh[r][d] * w;
            pa[i] += sc[r][d] * s;
        }
    }
    const float e1 = eta1p[0];
    #pragma unroll
    for (int i = 0; i < 2; ++i) {
        int r = r2 * 2 + i;
        float y = ya[i] + b1[hcol];
        sv[r][hcol] = y + e1 * tanhf(y) * pa[i];
    }
    __syncthreads();

    // LN(128) + gelu + c2: wave per row
    {
        int r = wv;
        float v0 = sv[r][lane];
        float v1 = sv[r][lane + 64];
        float s = v0 + v1, sq = v0 * v0 + v1 * v1;
        #pragma unroll
        for (int o = 32; o; o >>= 1) { s += __shfl_xor(s, o); sq += __shfl_xor(sq, o); }
        float mu = s * (1.f / 128.f);
        float var = sq * (1.f / 128.f) - mu * mu;
        float rs = rsqrtf(var + 1e-5f);
        float u0 = (v0 - mu) * rs * g1[lane] + be1[lane];
        float u1 = (v1 - mu) * rs * g1[lane + 64] + be1[lane + 64];
        float ge0 = gelu_f(u0);
        float ge1 = gelu_f(u1);
        float gsq = ge0 * ge0 + ge1 * ge1;
        #pragma unroll
        for (int o = 32; o; o >>= 1) gsq += __shfl_xor(gsq, o);
        float inv = 1.f / (sqrtf(gsq) + 1e-8f);
        sh2[r][lane] = ge0; sh2[r][lane + 64] = ge1;
        sc2[r][lane] = ge0 * ge0 * inv; sc2[r][lane + 64] = ge1 * ge1 * inv;
    }
    __syncthreads();

    // layer 2: 64 outputs x 4 rows; one item per thread
    const int h2c = t & 63;
    const int r4 = t >> 6;           // 0..3
    float yb = 0.f, pb = 0.f;
    for (int d = 0; d < 128; ++d) {
        yb += sh2[r4][d] * W2T[d * 64 + h2c];
        pb += sc2[r4][d] * S2T[d * 64 + h2c];
    }
    {
        const float e2 = eta2p[0];
        float y = yb + b2[h2c];
        sv2[r4][h2c] = y + e2 * tanhf(y) * pb;
    }
    __syncthreads();

    // LN(64) + gelu + head: wave per row
    {
        int r = wv;
        float v0 = sv2[r][lane];
        float s = v0, sq = v0 * v0;
        #pragma unroll
        for (int o = 32; o; o >>= 1) { s += __shfl_xor(s, o); sq += __shfl_xor(sq, o); }
        float mu = s * (1.f / 64.f);
        float var = sq * (1.f / 64.f) - mu * mu;
        float rs = rsqrtf(var + 1e-5f);
        float u = (v0 - mu) * rs * g2[lane] + be2[lane];
        float g = gelu_f(u);
        float hc = g * hw[lane];
        #pragma unroll
        for (int o = 32; o; o >>= 1) hc += __shfl_xor(hc, o);
        if (lane == 0) out[b0 + r] = hc + hbod[0];
    }
}

// ---------------------------------------------------------------------------
extern "C" void kernel_launch(void* const* d_in, const int* in_sizes, int n_in,
                              void* d_out, int out_size, void* d_ws, size_t ws_size,
                              hipStream_t stream)
{
    const float* x    = (const float*)d_in[0];
    const float* W0   = (const float*)d_in[1];
    const float* A0   = (const float*)d_in[2];
    const float* b0   = (const float*)d_in[3];
    const float* eta0 = (const float*)d_in[4];
    const float* g0   = (const float*)d_in[5];
    const float* be0  = (const float*)d_in[6];
    const float* W1   = (const float*)d_in[7];
    const float* A1   = (const float*)d_in[8];
    const float* b1   = (const float*)d_in[9];
    const float* eta1 = (const float*)d_in[10];
    const float* g1   = (const float*)d_in[11];
    const float* be1  = (const float*)d_in[12];
    const float* W2   = (const float*)d_in[13];
    const float* A2   = (const float*)d_in[14];
    const float* b2   = (const float*)d_in[15];
    const float* eta2 = (const float*)d_in[16];
    const float* g2   = (const float*)d_in[17];
    const float* be2  = (const float*)d_in[18];
    const float* hw   = (const float*)d_in[19];
    const float* hbod = (const float*)d_in[20];
    float* out = (float*)d_out;

    char* w = (char*)d_ws;
    unsigned short* hb  = (unsigned short*)(w + 0);          // 20971520
    unsigned short* cb  = (unsigned short*)(w + 20971520);   // 20971520
    unsigned short* Wb0 = (unsigned short*)(w + 41943040);   // 5242880
    unsigned short* Sb0 = (unsigned short*)(w + 47185920);   // 5242880
    float* Py  = (float*)(w + 52428800);                     // 16777216
    float* Pp  = (float*)(w + 69206016);                     // 16777216
    float* h1  = (float*)(w + 85983232);                     // 1048576
    float* c1  = (float*)(w + 87031808);                     // 1048576
    float* W1T = (float*)(w + 88080384);                     // 131072
    float* S1T = (float*)(w + 88211456);                     // 131072
    float* W2T = (float*)(w + 88342528);                     // 32768
    float* S2T = (float*)(w + 88375296);                     // 32768

    hipLaunchKernelGGL(fft_prep_kernel, dim3(3804), dim3(512), 0, stream,
                       x, hb, cb, W0, A0, Wb0, Sb0, W1, A1, W2, A2, W1T, S1T, W2T, S2T);
    hipLaunchKernelGGL(gemm0_kernel, dim3(8, 4, 16), dim3(256), 0, stream, hb, cb, Wb0, Sb0, Py, Pp);
    hipLaunchKernelGGL(combine0_kernel, dim3(1024), dim3(256), 0, stream, Py, Pp, b0, eta0, g0, be0, h1, c1);
    hipLaunchKernelGGL(tail_kernel, dim3(256), dim3(256), 0, stream, h1, c1, W1T, S1T, b1, eta1, g1, be1,
                       W2T, S2T, b2, eta2, g2, be2, hw, hbod, out);
}